// Round 1
// baseline (1255.567 us; speedup 1.0000x reference)
//
#include <hip/hip_runtime.h>
#include <hip/hip_bf16.h>
#include <math.h>

using bf16 = __hip_bfloat16;
typedef short bf16x8 __attribute__((ext_vector_type(8)));
typedef float f32x4 __attribute__((ext_vector_type(4)));

static constexpr int  TOK     = 100352;     // 32*56*56 tokens
static constexpr long QKV_SEG = 38535168L;  // TOK*384 elements per q/k/v segment

__device__ __forceinline__ float bf2f(short u) {
    return __uint_as_float(((unsigned)(unsigned short)u) << 16);
}

// ---------------------------------------------------------------------------
// LayerNorm over C=384, one wave per token. WINDOWED: destination token order
// is (b, window, intra-window) after roll(-3,-3); source is original x.
// ---------------------------------------------------------------------------
template<bool WINDOWED>
__global__ __launch_bounds__(256)
void ln_kernel(const float* __restrict__ x, const float* __restrict__ gw,
               const float* __restrict__ gb, bf16* __restrict__ out)
{
    const int wave = threadIdx.x >> 6;
    const int lane = threadIdx.x & 63;
    const long t = (long)blockIdx.x * 4 + wave;
    size_t src;
    if (WINDOWED) {
        int bb = (int)(t / 3136); int rem = (int)(t - (long)bb * 3136);
        int wIdx = rem / 49;      int n = rem - wIdx * 49;
        int wh = wIdx >> 3, ww = wIdx & 7;
        int yi = n / 7,     xi = n - yi * 7;
        int r = wh * 7 + yi + 3; if (r >= 56) r -= 56;   // roll(-3): src=(dst+3)%56
        int c = ww * 7 + xi + 3; if (c >= 56) c -= 56;
        src = ((size_t)bb * 3136 + (size_t)r * 56 + c) * 384;
    } else {
        src = (size_t)t * 384;
    }
    float v[6]; float s = 0.f, sq = 0.f;
    #pragma unroll
    for (int kk = 0; kk < 6; ++kk) {
        v[kk] = x[src + lane + 64 * kk];
        s += v[kk]; sq += v[kk] * v[kk];
    }
    #pragma unroll
    for (int o = 32; o > 0; o >>= 1) { s += __shfl_xor(s, o); sq += __shfl_xor(sq, o); }
    const float m   = s * (1.f / 384.f);
    const float var = sq * (1.f / 384.f) - m * m;
    const float rs  = rsqrtf(var + 1e-5f);
    #pragma unroll
    for (int kk = 0; kk < 6; ++kk) {
        int ch = lane + 64 * kk;
        out[(size_t)t * 384 + ch] = __float2bfloat16((v[kk] - m) * rs * gw[ch] + gb[ch]);
    }
}

// ---------------------------------------------------------------------------
// GEMM: C[M,N] = A[M,K](bf16) @ W[N,K]^T(fp32, converted on stage) + bias
// 128x128 tile, BK=64, 4 waves (2x2 of 64x64), mfma_f32_16x16x32_bf16.
// MODE 0: QKV  -> scatter to (s,w,h,n,d) bf16, scale q
// MODE 1: proj -> window-reverse + roll(+3) scatter, += x, fp32 out
// MODE 2: fc1  -> exact GELU, bf16 out (row stride 1536)
// MODE 3: fc2  -> += resid (in-place on out), fp32
// ---------------------------------------------------------------------------
template<int MODE>
__global__ __launch_bounds__(256)
void gemm_bt(const bf16* __restrict__ A, const float* __restrict__ W,
             const float* __restrict__ bias, bf16* __restrict__ outb,
             float* __restrict__ outf, const float* __restrict__ resid,
             int K, int tilesN)
{
    __shared__ bf16 As[128][72];
    __shared__ bf16 Bs[128][72];
    const int tm = blockIdx.x / tilesN;
    const int tn = blockIdx.x - tm * tilesN;
    const int tid  = threadIdx.x;
    const int lane = tid & 63;
    const int wid  = tid >> 6;
    const int wr = (wid >> 1) * 64;
    const int wc = (wid & 1) * 64;
    const int r0 = tid >> 3;          // 0..31
    const int c0 = (tid & 7) * 8;     // 0..56 step 8

    f32x4 acc[4][4];
    #pragma unroll
    for (int i = 0; i < 4; ++i)
        #pragma unroll
        for (int j = 0; j < 4; ++j) acc[i][j] = (f32x4)0.0f;

    const long am0 = (long)tm * 128;
    const int  bn0 = tn * 128;

    for (int k0 = 0; k0 < K; k0 += 64) {
        #pragma unroll
        for (int p = 0; p < 4; ++p) {
            const int row = p * 32 + r0;
            *(int4*)&As[row][c0] =
                *(const int4*)&A[(size_t)(am0 + row) * K + k0 + c0];
            const float4 f0 = *(const float4*)&W[(size_t)(bn0 + row) * K + k0 + c0];
            const float4 f1 = *(const float4*)&W[(size_t)(bn0 + row) * K + k0 + c0 + 4];
            union { bf16 h[8]; int4 v; } u;
            u.h[0] = __float2bfloat16(f0.x); u.h[1] = __float2bfloat16(f0.y);
            u.h[2] = __float2bfloat16(f0.z); u.h[3] = __float2bfloat16(f0.w);
            u.h[4] = __float2bfloat16(f1.x); u.h[5] = __float2bfloat16(f1.y);
            u.h[6] = __float2bfloat16(f1.z); u.h[7] = __float2bfloat16(f1.w);
            *(int4*)&Bs[row][c0] = u.v;
        }
        __syncthreads();
        #pragma unroll
        for (int kk = 0; kk < 2; ++kk) {
            const int kof = kk * 32 + (lane >> 4) * 8;
            bf16x8 aF[4], bF[4];
            #pragma unroll
            for (int mi = 0; mi < 4; ++mi)
                aF[mi] = *(const bf16x8*)&As[wr + mi * 16 + (lane & 15)][kof];
            #pragma unroll
            for (int ni = 0; ni < 4; ++ni)
                bF[ni] = *(const bf16x8*)&Bs[wc + ni * 16 + (lane & 15)][kof];
            #pragma unroll
            for (int mi = 0; mi < 4; ++mi)
                #pragma unroll
                for (int ni = 0; ni < 4; ++ni)
                    acc[mi][ni] = __builtin_amdgcn_mfma_f32_16x16x32_bf16(
                        aF[mi], bF[ni], acc[mi][ni], 0, 0, 0);
        }
        __syncthreads();
    }

    #pragma unroll
    for (int mi = 0; mi < 4; ++mi) {
      #pragma unroll
      for (int ni = 0; ni < 4; ++ni) {
        #pragma unroll
        for (int r = 0; r < 4; ++r) {
            const int row = wr + mi * 16 + ((lane >> 4) << 2) + r;
            const int col = wc + ni * 16 + (lane & 15);
            const long gm = am0 + row;
            const int  gn = bn0 + col;
            float val = acc[mi][ni][r] + bias[gn];
            if (MODE == 0) {
                int s3 = gn / 384; int rem = gn - s3 * 384;
                int hh = rem >> 5, d = rem & 31;
                long wwi = gm / 49; int n = (int)(gm - wwi * 49);
                size_t dst = (size_t)s3 * QKV_SEG
                           + ((size_t)(wwi * 12 + hh) * 49 + n) * 32 + d;
                if (s3 == 0) val *= 0.17677669529663687f;   // hd^-0.5
                outb[dst] = __float2bfloat16(val);
            } else if (MODE == 1) {
                int bb = (int)(gm / 3136); int rem = (int)(gm - (long)bb * 3136);
                int wIdx = rem / 49; int n = rem - wIdx * 49;
                int wh = wIdx >> 3, ww2 = wIdx & 7;
                int yi = n / 7,     xi = n - yi * 7;
                int rr = wh * 7 + yi + 3; if (rr >= 56) rr -= 56;  // roll(+3) back
                int cc = ww2 * 7 + xi + 3; if (cc >= 56) cc -= 56;
                size_t dst = ((size_t)bb * 3136 + (size_t)rr * 56 + cc) * 384 + gn;
                outf[dst] = resid[dst] + val;
            } else if (MODE == 2) {
                val = 0.5f * val * (1.f + erff(val * 0.70710678118654752f));
                outb[(size_t)gm * 1536 + gn] = __float2bfloat16(val);
            } else {
                size_t dst = (size_t)gm * 384 + gn;
                outf[dst] = resid[dst] + val;
            }
        }
      }
    }
}

// ---------------------------------------------------------------------------
// Windowed attention: one 128-thread block per (window, head).
// q,k,v: bf16 (w,h,n,d) layout; rel-pos bias + shift mask computed inline.
// ---------------------------------------------------------------------------
__global__ __launch_bounds__(128)
void attn_kernel(const bf16* __restrict__ q, const bf16* __restrict__ k,
                 const bf16* __restrict__ v, const float* __restrict__ table,
                 bf16* __restrict__ o)
{
    __shared__ bf16 qs[1568], ks[1568], vs[1568];
    __shared__ float S[2401];
    const int blk = blockIdx.x;           // w*12 + h
    const int w = blk / 12, h = blk - w * 12;
    const int wIdx = w & 63;
    const int wh = wIdx >> 3, ww = wIdx & 7;
    const size_t base = (size_t)blk * 1568;
    const int tid = threadIdx.x;

    for (int cdx = tid; cdx < 196; cdx += 128) {
        ((int4*)qs)[cdx] = ((const int4*)(q + base))[cdx];
        ((int4*)ks)[cdx] = ((const int4*)(k + base))[cdx];
        ((int4*)vs)[cdx] = ((const int4*)(v + base))[cdx];
    }
    __syncthreads();

    for (int e = tid; e < 2401; e += 128) {
        const int i = e / 49, j = e - i * 49;
        const bf16x8* qr = (const bf16x8*)&qs[i * 32];
        const bf16x8* kr = (const bf16x8*)&ks[j * 32];
        float acc = 0.f;
        #pragma unroll
        for (int ch = 0; ch < 4; ++ch) {
            bf16x8 qa = qr[ch], ka = kr[ch];
            #pragma unroll
            for (int u2 = 0; u2 < 8; ++u2)
                acc += bf2f(qa[u2]) * bf2f(ka[u2]);
        }
        const int yi = i / 7, xi = i - yi * 7;
        const int yj = j / 7, xj = j - yj * 7;
        const int ridx = (yi - yj + 6) * 13 + (xi - xj + 6);
        acc += table[ridx * 12 + h];
        const int idi = ((wh < 7) ? 0 : ((yi < 4) ? 1 : 2)) * 3
                      + ((ww < 7) ? 0 : ((xi < 4) ? 1 : 2));
        const int idj = ((wh < 7) ? 0 : ((yj < 4) ? 1 : 2)) * 3
                      + ((ww < 7) ? 0 : ((xj < 4) ? 1 : 2));
        if (idi != idj) acc -= 100.f;
        S[e] = acc;
    }
    __syncthreads();

    if (tid < 49) {
        float m = S[tid * 49];
        for (int j = 1; j < 49; ++j) m = fmaxf(m, S[tid * 49 + j]);
        float sum = 0.f;
        for (int j = 0; j < 49; ++j) {
            float p = __expf(S[tid * 49 + j] - m);
            S[tid * 49 + j] = p; sum += p;
        }
        const float inv = 1.0f / sum;
        for (int j = 0; j < 49; ++j) S[tid * 49 + j] *= inv;
    }
    __syncthreads();

    for (int task = tid; task < 196; task += 128) {
        const int i = task >> 2, dc = (task & 3) * 8;
        float a8[8] = {0.f,0.f,0.f,0.f,0.f,0.f,0.f,0.f};
        for (int j = 0; j < 49; ++j) {
            const float p = S[i * 49 + j];
            bf16x8 vv = *(const bf16x8*)&vs[j * 32 + dc];
            #pragma unroll
            for (int u2 = 0; u2 < 8; ++u2) a8[u2] += p * bf2f(vv[u2]);
        }
        union { bf16 hh[8]; int4 v4; } uu;
        #pragma unroll
        for (int u2 = 0; u2 < 8; ++u2) uu.hh[u2] = __float2bfloat16(a8[u2]);
        *(int4*)&o[((size_t)w * 49 + i) * 384 + h * 32 + dc] = uu.v4;
    }
}

// ---------------------------------------------------------------------------
extern "C" void kernel_launch(void* const* d_in, const int* in_sizes, int n_in,
                              void* d_out, int out_size, void* d_ws, size_t ws_size,
                              hipStream_t stream) {
    const float* x      = (const float*)d_in[0];
    const float* n1w    = (const float*)d_in[1];
    const float* n1b    = (const float*)d_in[2];
    const float* qkv_w  = (const float*)d_in[3];
    const float* qkv_b  = (const float*)d_in[4];
    const float* table  = (const float*)d_in[5];
    const float* proj_w = (const float*)d_in[6];
    const float* proj_b = (const float*)d_in[7];
    const float* n2w    = (const float*)d_in[8];
    const float* n2b    = (const float*)d_in[9];
    const float* fc1_w  = (const float*)d_in[10];
    const float* fc1_b  = (const float*)d_in[11];
    const float* fc2_w  = (const float*)d_in[12];
    const float* fc2_b  = (const float*)d_in[13];
    float* out = (float*)d_out;

    // ws layout (needs ~385.4 MB):
    //   buf0: TOK*384 bf16  (77,070,336 B)  -- hw / attn-out / ln2-out
    //   buf1: max(qkv 3*TOK*384 bf16, hid TOK*1536 bf16) = 308,281,344 B
    char* ws = (char*)d_ws;
    bf16* buf0 = (bf16*)ws;
    bf16* buf1 = (bf16*)(ws + 77070336);

    // 1) LN1 + roll + window partition -> buf0 (bf16)
    ln_kernel<true><<<TOK / 4, 256, 0, stream>>>(x, n1w, n1b, buf0);
    // 2) QKV GEMM -> buf1 (q|k|v segments, head-major)
    gemm_bt<0><<<784 * 9, 256, 0, stream>>>(buf0, qkv_w, qkv_b,
                                            buf1, nullptr, nullptr, 384, 9);
    // 3) windowed attention -> buf0
    attn_kernel<<<2048 * 12, 128, 0, stream>>>(buf1, buf1 + QKV_SEG,
                                               buf1 + 2 * QKV_SEG, table, buf0);
    // 4) proj GEMM + window reverse + roll + residual -> out (= y)
    gemm_bt<1><<<784 * 3, 256, 0, stream>>>(buf0, proj_w, proj_b,
                                            nullptr, out, x, 384, 3);
    // 5) LN2(y) -> buf0 (bf16)
    ln_kernel<false><<<TOK / 4, 256, 0, stream>>>(out, n2w, n2b, buf0);
    // 6) fc1 + GELU -> buf1 (hid, bf16)
    gemm_bt<2><<<784 * 12, 256, 0, stream>>>(buf0, fc1_w, fc1_b,
                                             buf1, nullptr, nullptr, 384, 12);
    // 7) fc2 + residual (in-place on out)
    gemm_bt<3><<<784 * 3, 256, 0, stream>>>(buf1, fc2_w, fc2_b,
                                            nullptr, out, out, 1536, 3);
}

// Round 2
// 1033.495 us; speedup vs baseline: 1.2149x; 1.2149x over previous
//
#include <hip/hip_runtime.h>
#include <hip/hip_bf16.h>
#include <math.h>

using bf16 = __hip_bfloat16;
typedef short bf16x8 __attribute__((ext_vector_type(8)));
typedef float f32x4 __attribute__((ext_vector_type(4)));

static constexpr int  TOK     = 100352;     // 32*56*56 tokens
static constexpr long QKV_SEG = 38535168L;  // TOK*384 elements per q/k/v segment

__device__ __forceinline__ float bf2f(short u) {
    return __uint_as_float(((unsigned)(unsigned short)u) << 16);
}
__device__ __forceinline__ short f2bs(float x) {
    union { bf16 b; short s; } u; u.b = __float2bfloat16(x); return u.s;
}
// async global->LDS, 16B per lane. LDS dest must be uniform base + lane*16.
__device__ __forceinline__ void gload16(const void* g, void* l) {
    __builtin_amdgcn_global_load_lds(
        (const __attribute__((address_space(1))) unsigned int*)g,
        (__attribute__((address_space(3))) unsigned int*)l, 16, 0, 0);
}

// ---------------------------------------------------------------------------
// Pre-convert all fp32 weights to bf16 (once per launch, ~7MB traffic).
// layout in out: qkv[0,442368) proj[442368,589824) fc1[589824,1179648) fc2[1179648,1769472)
// ---------------------------------------------------------------------------
__global__ __launch_bounds__(256)
void convert_w_kernel(const float* __restrict__ qkv_w, const float* __restrict__ proj_w,
                      const float* __restrict__ fc1_w, const float* __restrict__ fc2_w,
                      bf16* __restrict__ out)
{
    const int i4 = (blockIdx.x * 256 + threadIdx.x) * 4;
    if (i4 >= 1769472) return;
    const float* src; int off;
    if (i4 < 442368)       { src = qkv_w;  off = i4; }
    else if (i4 < 589824)  { src = proj_w; off = i4 - 442368; }
    else if (i4 < 1179648) { src = fc1_w;  off = i4 - 589824; }
    else                   { src = fc2_w;  off = i4 - 1179648; }
    const float4 v = *(const float4*)&src[off];
    out[i4+0] = __float2bfloat16(v.x);
    out[i4+1] = __float2bfloat16(v.y);
    out[i4+2] = __float2bfloat16(v.z);
    out[i4+3] = __float2bfloat16(v.w);
}

// ---------------------------------------------------------------------------
// LayerNorm over C=384, one wave per token. WINDOWED: dst order is
// (b, window, intra-window) after roll(-3,-3); source is original x.
// ---------------------------------------------------------------------------
template<bool WINDOWED>
__global__ __launch_bounds__(256)
void ln_kernel(const float* __restrict__ x, const float* __restrict__ gw,
               const float* __restrict__ gb, bf16* __restrict__ out)
{
    const int wave = threadIdx.x >> 6;
    const int lane = threadIdx.x & 63;
    const long t = (long)blockIdx.x * 4 + wave;
    size_t src;
    if (WINDOWED) {
        int bb = (int)(t / 3136); int rem = (int)(t - (long)bb * 3136);
        int wIdx = rem / 49;      int n = rem - wIdx * 49;
        int wh = wIdx >> 3, ww = wIdx & 7;
        int yi = n / 7,     xi = n - yi * 7;
        int r = wh * 7 + yi + 3; if (r >= 56) r -= 56;
        int c = ww * 7 + xi + 3; if (c >= 56) c -= 56;
        src = ((size_t)bb * 3136 + (size_t)r * 56 + c) * 384;
    } else {
        src = (size_t)t * 384;
    }
    float v[6]; float s = 0.f, sq = 0.f;
    #pragma unroll
    for (int kk = 0; kk < 6; ++kk) {
        v[kk] = x[src + lane + 64 * kk];
        s += v[kk]; sq += v[kk] * v[kk];
    }
    #pragma unroll
    for (int o = 32; o > 0; o >>= 1) { s += __shfl_xor(s, o); sq += __shfl_xor(sq, o); }
    const float m   = s * (1.f / 384.f);
    const float var = sq * (1.f / 384.f) - m * m;
    const float rs  = rsqrtf(var + 1e-5f);
    #pragma unroll
    for (int kk = 0; kk < 6; ++kk) {
        int ch = lane + 64 * kk;
        out[(size_t)t * 384 + ch] = __float2bfloat16((v[kk] - m) * rs * gw[ch] + gb[ch]);
    }
}

// ---------------------------------------------------------------------------
// GEMM: C[M,N] = A[M,K](bf16) @ W[N,K]^T(bf16) + bias; m97 structure:
// global_load_lds width-16 staging, linear LDS [128][64], 4 waves 2x2.
// XCD-aware block swizzle (grids are %8==0).
// ---------------------------------------------------------------------------
template<int MODE>
__global__ __launch_bounds__(256)
void gemm_bt(const bf16* __restrict__ A, const bf16* __restrict__ W,
             const float* __restrict__ bias, bf16* __restrict__ outb,
             float* __restrict__ outf, const float* __restrict__ resid,
             int K, int tilesN)
{
    __shared__ bf16 As[128 * 64];
    __shared__ bf16 Bs[128 * 64];
    const int nwg = gridDim.x;
    const int b0  = blockIdx.x;
    const int swz = (b0 & 7) * (nwg >> 3) + (b0 >> 3);
    const int tm = swz / tilesN;
    const int tn = swz - tm * tilesN;
    const int tid  = threadIdx.x;
    const int lane = tid & 63;
    const int wid  = tid >> 6;
    const int wr = (wid >> 1) * 64;
    const int wc = (wid & 1) * 64;
    const int sr = tid >> 3;          // staging row 0..31
    const int sc = (tid & 7) * 8;     // staging col 0..56 step 8

    f32x4 acc[4][4];
    #pragma unroll
    for (int i = 0; i < 4; ++i)
        #pragma unroll
        for (int j = 0; j < 4; ++j) acc[i][j] = (f32x4)0.0f;

    const long am0 = (long)tm * 128;
    const int  bn0 = tn * 128;

    for (int k0 = 0; k0 < K; k0 += 64) {
        #pragma unroll
        for (int p = 0; p < 4; ++p) {
            const int row = p * 32 + sr;
            gload16(&A[(size_t)(am0 + row) * K + k0 + sc], &As[row * 64 + sc]);
            gload16(&W[(size_t)(bn0 + row) * K + k0 + sc], &Bs[row * 64 + sc]);
        }
        __syncthreads();
        #pragma unroll
        for (int kk = 0; kk < 2; ++kk) {
            const int kof = kk * 32 + (lane >> 4) * 8;
            bf16x8 aF[4], bF[4];
            #pragma unroll
            for (int mi = 0; mi < 4; ++mi)
                aF[mi] = *(const bf16x8*)&As[(wr + mi * 16 + (lane & 15)) * 64 + kof];
            #pragma unroll
            for (int ni = 0; ni < 4; ++ni)
                bF[ni] = *(const bf16x8*)&Bs[(wc + ni * 16 + (lane & 15)) * 64 + kof];
            #pragma unroll
            for (int mi = 0; mi < 4; ++mi)
                #pragma unroll
                for (int ni = 0; ni < 4; ++ni)
                    acc[mi][ni] = __builtin_amdgcn_mfma_f32_16x16x32_bf16(
                        aF[mi], bF[ni], acc[mi][ni], 0, 0, 0);
        }
        __syncthreads();
    }

    #pragma unroll
    for (int mi = 0; mi < 4; ++mi) {
      #pragma unroll
      for (int ni = 0; ni < 4; ++ni) {
        #pragma unroll
        for (int r = 0; r < 4; ++r) {
            const int row = wr + mi * 16 + ((lane >> 4) << 2) + r;
            const int col = wc + ni * 16 + (lane & 15);
            const long gm = am0 + row;
            const int  gn = bn0 + col;
            float val = acc[mi][ni][r] + bias[gn];
            if (MODE == 0) {
                int s3 = gn / 384; int rem = gn - s3 * 384;
                int hh = rem >> 5, d = rem & 31;
                long wwi = gm / 49; int n = (int)(gm - wwi * 49);
                size_t dst = (size_t)s3 * QKV_SEG
                           + ((size_t)(wwi * 12 + hh) * 49 + n) * 32 + d;
                if (s3 == 0) val *= 0.17677669529663687f;   // hd^-0.5
                outb[dst] = __float2bfloat16(val);
            } else if (MODE == 1) {
                int bb = (int)(gm / 3136); int rem = (int)(gm - (long)bb * 3136);
                int wIdx = rem / 49; int n = rem - wIdx * 49;
                int wh = wIdx >> 3, ww2 = wIdx & 7;
                int yi = n / 7,     xi = n - yi * 7;
                int rr = wh * 7 + yi + 3; if (rr >= 56) rr -= 56;
                int cc = ww2 * 7 + xi + 3; if (cc >= 56) cc -= 56;
                size_t dst = ((size_t)bb * 3136 + (size_t)rr * 56 + cc) * 384 + gn;
                outf[dst] = resid[dst] + val;
            } else if (MODE == 2) {
                val = 0.5f * val * (1.f + erff(val * 0.70710678118654752f));
                outb[(size_t)gm * 1536 + gn] = __float2bfloat16(val);
            } else {
                size_t dst = (size_t)gm * 384 + gn;
                outf[dst] = resid[dst] + val;
            }
        }
      }
    }
}

// ---------------------------------------------------------------------------
// MFMA windowed attention. 4 waves/block, one (window,head) per wave.
// Swapped QK^T: S^T = mfma(A=K, B=Q) -> lane owns query col i=lane&15 (+ni*16).
// Softmax: 16 in-lane + shfl_xor(16,32). P -> LDS row-major (XOR-swizzled).
// PV: O^T = mfma(A=V^T(LDS, swizzled), B=P(LDS)).
// No __syncthreads: all LDS regions are per-wave.
// ---------------------------------------------------------------------------
__global__ __launch_bounds__(256)
void attn_mfma(const bf16* __restrict__ q, const bf16* __restrict__ k,
               const bf16* __restrict__ v, const float* __restrict__ table,
               bf16* __restrict__ o)
{
    __shared__ bf16  vt_s[4][2048];   // per wave: V^T [32 d][64 j], 4KB, swizzled
    __shared__ bf16  p_s[4][4096];    // per wave: P   [64 i][64 j], 8KB, swizzled
    __shared__ float tbl_s[4][169];   // per wave: bias table column h

    const int tid  = threadIdx.x;
    const int wid  = tid >> 6;
    const int lane = tid & 63;
    const int li = lane & 15, g = lane >> 4;
    const int gwh = blockIdx.x * 4 + wid;       // global (window*12 + head)
    const int w = gwh / 12, h = gwh - w * 12;
    const int wIdx = w & 63;
    const int bh = wIdx >> 3, bw = wIdx & 7;    // window coords in 8x8 grid
    const size_t base = (size_t)gwh * 1568;     // 49*32 elems

    char* vt = (char*)vt_s[wid];
    char* ps = (char*)p_s[wid];

    // stage bias table column h (169 floats)
    for (int t = lane; t < 169; t += 64) tbl_s[wid][t] = table[t * 12 + h];

    // zero V^T (so cols j>=49 contribute exactly 0), then stage transposed
    {
        const int4 z = {0, 0, 0, 0};
        #pragma unroll
        for (int t = 0; t < 4; ++t) ((int4*)vt)[t * 64 + lane] = z;
        for (int t = lane; t < 196; t += 64) {
            const int j = t >> 2, d0 = (t & 3) * 8;
            bf16x8 row = *(const bf16x8*)&v[base + (size_t)j * 32 + d0];
            #pragma unroll
            for (int u = 0; u < 8; ++u) {
                const int d = d0 + u;
                int off = (d << 7) + (j << 1);
                off ^= (d & 7) << 4;
                *(short*)(vt + off) = row[u];
            }
        }
    }

    // ---- QK^T (swapped): acc[mj][ni] holds S^T[j][i] ----
    bf16x8 aK[4], bQ[4];
    const int koff = g * 8;
    #pragma unroll
    for (int mj = 0; mj < 4; ++mj)
        aK[mj] = *(const bf16x8*)&k[base + (size_t)(mj * 16 + li) * 32 + koff];
    #pragma unroll
    for (int ni = 0; ni < 4; ++ni)
        bQ[ni] = *(const bf16x8*)&q[base + (size_t)(ni * 16 + li) * 32 + koff];

    f32x4 acc[4][4];
    #pragma unroll
    for (int i = 0; i < 4; ++i)
        #pragma unroll
        for (int j = 0; j < 4; ++j) acc[i][j] = (f32x4)0.0f;
    #pragma unroll
    for (int mj = 0; mj < 4; ++mj)
        #pragma unroll
        for (int ni = 0; ni < 4; ++ni)
            acc[mj][ni] = __builtin_amdgcn_mfma_f32_16x16x32_bf16(
                aK[mj], bQ[ni], acc[mj][ni], 0, 0, 0);

    // ---- softmax over j per query i (i = ni*16+li; j = mj*16+g*4+r) ----
    const bool bndH = (bh == 7), bndW = (bw == 7);
    #pragma unroll
    for (int ni = 0; ni < 4; ++ni) {
        const int i = ni * 16 + li;
        const int yi = i / 7, xi = i - yi * 7;
        const int ri = (bndH ? (yi < 4 ? 3 : 6) : 0) + (bndW ? (xi < 4 ? 1 : 2) : 0);
        float mx = -1e30f;
        #pragma unroll
        for (int mj = 0; mj < 4; ++mj)
            #pragma unroll
            for (int r = 0; r < 4; ++r) {
                const int j = mj * 16 + g * 4 + r;
                const int yj = j / 7, xj = j - yj * 7;
                int ridx = (yi - yj + 6) * 13 + (xi - xj + 6);
                ridx = max(0, min(168, ridx));
                float val = acc[mj][ni][r] + tbl_s[wid][ridx];
                const int rj = (bndH ? (yj < 4 ? 3 : 6) : 0) + (bndW ? (xj < 4 ? 1 : 2) : 0);
                if (ri != rj) val -= 100.f;
                if (j >= 49) val = -1e30f;
                acc[mj][ni][r] = val;
                mx = fmaxf(mx, val);
            }
        mx = fmaxf(mx, __shfl_xor(mx, 16));
        mx = fmaxf(mx, __shfl_xor(mx, 32));
        float sum = 0.f;
        #pragma unroll
        for (int mj = 0; mj < 4; ++mj)
            #pragma unroll
            for (int r = 0; r < 4; ++r) {
                const float p = __expf(acc[mj][ni][r] - mx);
                acc[mj][ni][r] = p; sum += p;
            }
        sum += __shfl_xor(sum, 16);
        sum += __shfl_xor(sum, 32);
        const float inv = 1.f / sum;
        #pragma unroll
        for (int mj = 0; mj < 4; ++mj) {
            union { short h4[4]; uint2 u2; } pk;
            #pragma unroll
            for (int r = 0; r < 4; ++r) pk.h4[r] = f2bs(acc[mj][ni][r] * inv);
            int off = (i << 7) + ((mj * 16 + g * 4) << 1);
            off ^= (i & 7) << 4;
            *(uint2*)(ps + off) = pk.u2;
        }
    }

    // ---- PV: acc2[md][ni] = O^T[d][i] = sum_j V^T[d][j] * P[i][j] ----
    f32x4 acc2[2][4];
    #pragma unroll
    for (int i = 0; i < 2; ++i)
        #pragma unroll
        for (int j = 0; j < 4; ++j) acc2[i][j] = (f32x4)0.0f;
    #pragma unroll
    for (int kk = 0; kk < 2; ++kk) {
        bf16x8 aV[2], bP[4];
        #pragma unroll
        for (int md = 0; md < 2; ++md) {
            const int d = md * 16 + li;
            int off = (d << 7) + kk * 64 + g * 16;
            off ^= (d & 7) << 4;
            aV[md] = *(const bf16x8*)(vt + off);
        }
        #pragma unroll
        for (int ni = 0; ni < 4; ++ni) {
            const int i = ni * 16 + li;
            int off = (i << 7) + kk * 64 + g * 16;
            off ^= (i & 7) << 4;
            bP[ni] = *(const bf16x8*)(ps + off);
        }
        #pragma unroll
        for (int md = 0; md < 2; ++md)
            #pragma unroll
            for (int ni = 0; ni < 4; ++ni)
                acc2[md][ni] = __builtin_amdgcn_mfma_f32_16x16x32_bf16(
                    aV[md], bP[ni], acc2[md][ni], 0, 0, 0);
    }

    // ---- store O[i][d] (token-major, channel h*32+d) ----
    const size_t obase = (size_t)w * 49 * 384 + h * 32;
    #pragma unroll
    for (int ni = 0; ni < 4; ++ni) {
        const int i = ni * 16 + li;
        if (i < 49) {
            #pragma unroll
            for (int md = 0; md < 2; ++md) {
                const int d0 = md * 16 + g * 4;
                union { short h4[4]; uint2 u2; } pk;
                #pragma unroll
                for (int r = 0; r < 4; ++r) pk.h4[r] = f2bs(acc2[md][ni][r]);
                *(uint2*)&o[obase + (size_t)i * 384 + d0] = pk.u2;
            }
        }
    }
}

// ---------------------------------------------------------------------------
extern "C" void kernel_launch(void* const* d_in, const int* in_sizes, int n_in,
                              void* d_out, int out_size, void* d_ws, size_t ws_size,
                              hipStream_t stream) {
    const float* x      = (const float*)d_in[0];
    const float* n1w    = (const float*)d_in[1];
    const float* n1b    = (const float*)d_in[2];
    const float* qkv_w  = (const float*)d_in[3];
    const float* qkv_b  = (const float*)d_in[4];
    const float* table  = (const float*)d_in[5];
    const float* proj_w = (const float*)d_in[6];
    const float* proj_b = (const float*)d_in[7];
    const float* n2w    = (const float*)d_in[8];
    const float* n2b    = (const float*)d_in[9];
    const float* fc1_w  = (const float*)d_in[10];
    const float* fc1_b  = (const float*)d_in[11];
    const float* fc2_w  = (const float*)d_in[12];
    const float* fc2_b  = (const float*)d_in[13];
    float* out = (float*)d_out;

    // ws layout (~392.4 MB):
    //   buf0: TOK*384 bf16 (77,070,336 B)   -- hw / attn-out / ln2-out
    //   buf1: max(qkv 3*TOK*384, hid TOK*1536) bf16 = 308,281,344 B
    //   wb  : bf16 weights (7,077,888 B)
    char* ws = (char*)d_ws;
    bf16* buf0 = (bf16*)ws;
    bf16* buf1 = (bf16*)(ws + 77070336);
    bf16* wb   = (bf16*)(ws + 77070336 + 308281344);

    convert_w_kernel<<<1728, 256, 0, stream>>>(qkv_w, proj_w, fc1_w, fc2_w, wb);
    // 1) LN1 + roll + window partition -> buf0 (bf16)
    ln_kernel<true><<<TOK / 4, 256, 0, stream>>>(x, n1w, n1b, buf0);
    // 2) QKV GEMM -> buf1 (q|k|v segments, head-major)
    gemm_bt<0><<<784 * 9, 256, 0, stream>>>(buf0, wb, qkv_b,
                                            buf1, nullptr, nullptr, 384, 9);
    // 3) MFMA windowed attention -> buf0
    attn_mfma<<<2048 * 12 / 4, 256, 0, stream>>>(buf1, buf1 + QKV_SEG,
                                                 buf1 + 2 * QKV_SEG, table, buf0);
    // 4) proj GEMM + window reverse + roll + residual -> out (= y)
    gemm_bt<1><<<784 * 3, 256, 0, stream>>>(buf0, wb + 442368, proj_b,
                                            nullptr, out, x, 384, 3);
    // 5) LN2(y) -> buf0 (bf16)
    ln_kernel<false><<<TOK / 4, 256, 0, stream>>>(out, n2w, n2b, buf0);
    // 6) fc1 + GELU -> buf1 (hid, bf16)
    gemm_bt<2><<<784 * 12, 256, 0, stream>>>(buf0, wb + 589824, fc1_b,
                                             buf1, nullptr, nullptr, 384, 12);
    // 7) fc2 + residual (in-place on out)
    gemm_bt<3><<<784 * 3, 256, 0, stream>>>(buf1, wb + 1179648, fc2_b,
                                            nullptr, out, out, 1536, 3);
}

// Round 3
// 1009.955 us; speedup vs baseline: 1.2432x; 1.0233x over previous
//
#include <hip/hip_runtime.h>
#include <hip/hip_bf16.h>
#include <math.h>

using bf16 = __hip_bfloat16;
typedef short bf16x8 __attribute__((ext_vector_type(8)));
typedef float f32x4 __attribute__((ext_vector_type(4)));

static constexpr int  TOK     = 100352;     // 32*56*56 tokens
static constexpr long QKV_SEG = 38535168L;  // TOK*384 elements per q/k/v segment

__device__ __forceinline__ float bf2f(short u) {
    return __uint_as_float(((unsigned)(unsigned short)u) << 16);
}
__device__ __forceinline__ short f2bs(float x) {
    union { bf16 b; short s; } u; u.b = __float2bfloat16(x); return u.s;
}
// async global->LDS, 16B per lane. LDS dest must be uniform base + lane*16.
__device__ __forceinline__ void gload16(const void* g, void* l) {
    __builtin_amdgcn_global_load_lds(
        (const __attribute__((address_space(1))) unsigned int*)g,
        (__attribute__((address_space(3))) unsigned int*)l, 16, 0, 0);
}
// tanh-form GELU: x * sigmoid(1.5957691x + 0.071354816x^3); max |err| ~1e-3
__device__ __forceinline__ float gelu_fast(float x) {
    const float x2 = x * x;
    const float t1 = x * x2;
    const float y  = fmaf(0.071354816222f, t1, 1.5957691216f * x);
    const float e  = __expf(-y);
    return x * __frcp_rn(1.f + e);
}

// ---------------------------------------------------------------------------
// Pre-convert all fp32 weights to bf16 (once per launch, ~7MB traffic).
// layout: qkv[0,442368) proj[442368,589824) fc1[589824,1179648) fc2[1179648,1769472)
// ---------------------------------------------------------------------------
__global__ __launch_bounds__(256)
void convert_w_kernel(const float* __restrict__ qkv_w, const float* __restrict__ proj_w,
                      const float* __restrict__ fc1_w, const float* __restrict__ fc2_w,
                      bf16* __restrict__ out)
{
    const int i4 = (blockIdx.x * 256 + threadIdx.x) * 4;
    if (i4 >= 1769472) return;
    const float* src; int off;
    if (i4 < 442368)       { src = qkv_w;  off = i4; }
    else if (i4 < 589824)  { src = proj_w; off = i4 - 442368; }
    else if (i4 < 1179648) { src = fc1_w;  off = i4 - 589824; }
    else                   { src = fc2_w;  off = i4 - 1179648; }
    const float4 v = *(const float4*)&src[off];
    out[i4+0] = __float2bfloat16(v.x);
    out[i4+1] = __float2bfloat16(v.y);
    out[i4+2] = __float2bfloat16(v.z);
    out[i4+3] = __float2bfloat16(v.w);
}

// ---------------------------------------------------------------------------
// LayerNorm over C=384, one wave per token. WINDOWED: dst order is
// (b, window, intra-window) after roll(-3,-3); source is original x.
// ---------------------------------------------------------------------------
template<bool WINDOWED>
__global__ __launch_bounds__(256)
void ln_kernel(const float* __restrict__ x, const float* __restrict__ gw,
               const float* __restrict__ gb, bf16* __restrict__ out)
{
    const int wave = threadIdx.x >> 6;
    const int lane = threadIdx.x & 63;
    const long t = (long)blockIdx.x * 4 + wave;
    size_t src;
    if (WINDOWED) {
        int bb = (int)(t / 3136); int rem = (int)(t - (long)bb * 3136);
        int wIdx = rem / 49;      int n = rem - wIdx * 49;
        int wh = wIdx >> 3, ww = wIdx & 7;
        int yi = n / 7,     xi = n - yi * 7;
        int r = wh * 7 + yi + 3; if (r >= 56) r -= 56;
        int c = ww * 7 + xi + 3; if (c >= 56) c -= 56;
        src = ((size_t)bb * 3136 + (size_t)r * 56 + c) * 384;
    } else {
        src = (size_t)t * 384;
    }
    float v[6]; float s = 0.f, sq = 0.f;
    #pragma unroll
    for (int kk = 0; kk < 6; ++kk) {
        v[kk] = x[src + lane + 64 * kk];
        s += v[kk]; sq += v[kk] * v[kk];
    }
    #pragma unroll
    for (int o = 32; o > 0; o >>= 1) { s += __shfl_xor(s, o); sq += __shfl_xor(sq, o); }
    const float m   = s * (1.f / 384.f);
    const float var = sq * (1.f / 384.f) - m * m;
    const float rs  = rsqrtf(var + 1e-5f);
    #pragma unroll
    for (int kk = 0; kk < 6; ++kk) {
        int ch = lane + 64 * kk;
        out[(size_t)t * 384 + ch] = __float2bfloat16((v[kk] - m) * rs * gw[ch] + gb[ch]);
    }
}

// ---------------------------------------------------------------------------
// GEMM: C[M,N] = A[M,K](bf16) @ W[N,K]^T(bf16) + bias.
// 128x128 tile, BK=64, 4 waves 2x2, global_load_lds staging, XCD swizzle.
// MFMA operands SWAPPED (A-op = W rows, B-op = act rows) so the C/D layout
// gives each lane 4 CONSECUTIVE output features at one token -> vector stores.
// MODE 0: QKV  -> scatter (s,w,h,n,d) bf16, scale q       (uint2 stores)
// MODE 1: proj -> window-reverse+roll scatter, += x, fp32 (float4)
// MODE 2: fc1  -> fast GELU, bf16                         (uint2)
// MODE 3: fc2  -> += resid, fp32                          (float4)
// ---------------------------------------------------------------------------
template<int MODE>
__global__ __launch_bounds__(256)
void gemm_bt(const bf16* __restrict__ A, const bf16* __restrict__ W,
             const float* __restrict__ bias, bf16* __restrict__ outb,
             float* __restrict__ outf, const float* __restrict__ resid,
             int K, int tilesN)
{
    __shared__ bf16 As[128 * 64];
    __shared__ bf16 Bs[128 * 64];
    const int nwg = gridDim.x;
    const int b0  = blockIdx.x;
    const int swz = (b0 & 7) * (nwg >> 3) + (b0 >> 3);
    const int tm = swz / tilesN;
    const int tn = swz - tm * tilesN;
    const int tid  = threadIdx.x;
    const int lane = tid & 63;
    const int wid  = tid >> 6;
    const int wr = (wid >> 1) * 64;   // M offset of wave tile
    const int wc = (wid & 1) * 64;    // N offset of wave tile
    const int sr = tid >> 3;          // staging row 0..31
    const int sc = (tid & 7) * 8;     // staging col 0..56 step 8

    f32x4 acc[4][4];                  // [nf][mf]: row=n (4 consec per lane), col=m
    #pragma unroll
    for (int i = 0; i < 4; ++i)
        #pragma unroll
        for (int j = 0; j < 4; ++j) acc[i][j] = (f32x4)0.0f;

    const long am0 = (long)tm * 128;
    const int  bn0 = tn * 128;

    for (int k0 = 0; k0 < K; k0 += 64) {
        #pragma unroll
        for (int p = 0; p < 4; ++p) {
            const int row = p * 32 + sr;
            gload16(&A[(size_t)(am0 + row) * K + k0 + sc], &As[row * 64 + sc]);
            gload16(&W[(size_t)(bn0 + row) * K + k0 + sc], &Bs[row * 64 + sc]);
        }
        __syncthreads();
        #pragma unroll
        for (int kk = 0; kk < 2; ++kk) {
            const int kof = kk * 32 + (lane >> 4) * 8;
            bf16x8 aF[4], bF[4];
            #pragma unroll
            for (int mi = 0; mi < 4; ++mi)
                aF[mi] = *(const bf16x8*)&As[(wr + mi * 16 + (lane & 15)) * 64 + kof];
            #pragma unroll
            for (int ni = 0; ni < 4; ++ni)
                bF[ni] = *(const bf16x8*)&Bs[(wc + ni * 16 + (lane & 15)) * 64 + kof];
            #pragma unroll
            for (int ni = 0; ni < 4; ++ni)
                #pragma unroll
                for (int mi = 0; mi < 4; ++mi)
                    acc[ni][mi] = __builtin_amdgcn_mfma_f32_16x16x32_bf16(
                        bF[ni], aF[mi], acc[ni][mi], 0, 0, 0);
        }
        __syncthreads();
    }

    // epilogue: lane holds features n0..n0+3 at token gm, per fragment pair
    #pragma unroll
    for (int nf = 0; nf < 4; ++nf) {
        const int gn0 = bn0 + wc + nf * 16 + ((lane >> 4) << 2);  // 4-aligned
        const float4 bv = *(const float4*)&bias[gn0];
        // MODE 0 per-feature-group constants
        int s3 = 0, hh = 0, d0 = 0;
        if (MODE == 0) {
            s3 = gn0 / 384; const int rem = gn0 - s3 * 384;
            hh = rem >> 5; d0 = rem & 31;
        }
        #pragma unroll
        for (int mf = 0; mf < 4; ++mf) {
            const long gm = am0 + wr + mf * 16 + (lane & 15);
            float vals[4];
            #pragma unroll
            for (int r = 0; r < 4; ++r) vals[r] = acc[nf][mf][r] + ((const float*)&bv)[r];

            if (MODE == 0) {
                long wwi = gm / 49; int ntok = (int)(gm - wwi * 49);
                size_t dst = (size_t)s3 * QKV_SEG
                           + ((size_t)(wwi * 12 + hh) * 49 + ntok) * 32 + d0;
                union { short h4[4]; uint2 u2; } pk;
                if (s3 == 0) {
                    #pragma unroll
                    for (int r = 0; r < 4; ++r)
                        pk.h4[r] = f2bs(vals[r] * 0.17677669529663687f);
                } else {
                    #pragma unroll
                    for (int r = 0; r < 4; ++r) pk.h4[r] = f2bs(vals[r]);
                }
                *(uint2*)&outb[dst] = pk.u2;
            } else if (MODE == 1) {
                int bb = (int)(gm / 3136); int rem = (int)(gm - (long)bb * 3136);
                int wIdx = rem / 49; int n = rem - wIdx * 49;
                int wh = wIdx >> 3, ww2 = wIdx & 7;
                int yi = n / 7,     xi = n - yi * 7;
                int rr = wh * 7 + yi + 3; if (rr >= 56) rr -= 56;
                int cc = ww2 * 7 + xi + 3; if (cc >= 56) cc -= 56;
                size_t dst = ((size_t)bb * 3136 + (size_t)rr * 56 + cc) * 384 + gn0;
                const float4 rv = *(const float4*)&resid[dst];
                float4 ov;
                ov.x = rv.x + vals[0]; ov.y = rv.y + vals[1];
                ov.z = rv.z + vals[2]; ov.w = rv.w + vals[3];
                *(float4*)&outf[dst] = ov;
            } else if (MODE == 2) {
                union { short h4[4]; uint2 u2; } pk;
                #pragma unroll
                for (int r = 0; r < 4; ++r) pk.h4[r] = f2bs(gelu_fast(vals[r]));
                *(uint2*)&outb[(size_t)gm * 1536 + gn0] = pk.u2;
            } else {
                size_t dst = (size_t)gm * 384 + gn0;
                const float4 rv = *(const float4*)&resid[dst];
                float4 ov;
                ov.x = rv.x + vals[0]; ov.y = rv.y + vals[1];
                ov.z = rv.z + vals[2]; ov.w = rv.w + vals[3];
                *(float4*)&outf[dst] = ov;
            }
        }
    }
}

// ---------------------------------------------------------------------------
// MFMA windowed attention. 4 waves/block, one (window,head) per wave.
// Swapped QK^T: S^T = mfma(A=K, B=Q) -> lane owns query col i. Softmax:
// 16 in-lane + shfl_xor(16,32). P -> LDS (XOR-swizzled). PV: O^T = mfma(V^T, P).
// ---------------------------------------------------------------------------
__global__ __launch_bounds__(256)
void attn_mfma(const bf16* __restrict__ q, const bf16* __restrict__ k,
               const bf16* __restrict__ v, const float* __restrict__ table,
               bf16* __restrict__ o)
{
    __shared__ bf16  vt_s[4][2048];   // per wave: V^T [32 d][64 j], swizzled
    __shared__ bf16  p_s[4][4096];    // per wave: P   [64 i][64 j], swizzled
    __shared__ float tbl_s[4][169];

    const int tid  = threadIdx.x;
    const int wid  = tid >> 6;
    const int lane = tid & 63;
    const int li = lane & 15, g = lane >> 4;
    const int gwh = blockIdx.x * 4 + wid;       // window*12 + head
    const int w = gwh / 12, h = gwh - w * 12;
    const int wIdx = w & 63;
    const int bh = wIdx >> 3, bw = wIdx & 7;
    const size_t base = (size_t)gwh * 1568;

    char* vt = (char*)vt_s[wid];
    char* ps = (char*)p_s[wid];

    for (int t = lane; t < 169; t += 64) tbl_s[wid][t] = table[t * 12 + h];

    {
        const int4 z = {0, 0, 0, 0};
        #pragma unroll
        for (int t = 0; t < 4; ++t) ((int4*)vt)[t * 64 + lane] = z;
        for (int t = lane; t < 196; t += 64) {
            const int j = t >> 2, d0 = (t & 3) * 8;
            bf16x8 row = *(const bf16x8*)&v[base + (size_t)j * 32 + d0];
            #pragma unroll
            for (int u = 0; u < 8; ++u) {
                const int d = d0 + u;
                int off = (d << 7) + (j << 1);
                off ^= (d & 7) << 4;
                *(short*)(vt + off) = row[u];
            }
        }
    }

    // QK^T (swapped): acc[mj][ni] = S^T[j][i]
    bf16x8 aK[4], bQ[4];
    const int koff = g * 8;
    #pragma unroll
    for (int mj = 0; mj < 4; ++mj)
        aK[mj] = *(const bf16x8*)&k[base + (size_t)(mj * 16 + li) * 32 + koff];
    #pragma unroll
    for (int ni = 0; ni < 4; ++ni)
        bQ[ni] = *(const bf16x8*)&q[base + (size_t)(ni * 16 + li) * 32 + koff];

    f32x4 acc[4][4];
    #pragma unroll
    for (int i = 0; i < 4; ++i)
        #pragma unroll
        for (int j = 0; j < 4; ++j) acc[i][j] = (f32x4)0.0f;
    #pragma unroll
    for (int mj = 0; mj < 4; ++mj)
        #pragma unroll
        for (int ni = 0; ni < 4; ++ni)
            acc[mj][ni] = __builtin_amdgcn_mfma_f32_16x16x32_bf16(
                aK[mj], bQ[ni], acc[mj][ni], 0, 0, 0);

    // softmax over j per query i
    const bool bndH = (bh == 7), bndW = (bw == 7);
    #pragma unroll
    for (int ni = 0; ni < 4; ++ni) {
        const int i = ni * 16 + li;
        const int yi = i / 7, xi = i - yi * 7;
        const int ri = (bndH ? (yi < 4 ? 3 : 6) : 0) + (bndW ? (xi < 4 ? 1 : 2) : 0);
        float mx = -1e30f;
        #pragma unroll
        for (int mj = 0; mj < 4; ++mj)
            #pragma unroll
            for (int r = 0; r < 4; ++r) {
                const int j = mj * 16 + g * 4 + r;
                const int yj = j / 7, xj = j - yj * 7;
                int ridx = (yi - yj + 6) * 13 + (xi - xj + 6);
                ridx = max(0, min(168, ridx));
                float val = acc[mj][ni][r] + tbl_s[wid][ridx];
                const int rj = (bndH ? (yj < 4 ? 3 : 6) : 0) + (bndW ? (xj < 4 ? 1 : 2) : 0);
                if (ri != rj) val -= 100.f;
                if (j >= 49) val = -1e30f;
                acc[mj][ni][r] = val;
                mx = fmaxf(mx, val);
            }
        mx = fmaxf(mx, __shfl_xor(mx, 16));
        mx = fmaxf(mx, __shfl_xor(mx, 32));
        float sum = 0.f;
        #pragma unroll
        for (int mj = 0; mj < 4; ++mj)
            #pragma unroll
            for (int r = 0; r < 4; ++r) {
                const float p = __expf(acc[mj][ni][r] - mx);
                acc[mj][ni][r] = p; sum += p;
            }
        sum += __shfl_xor(sum, 16);
        sum += __shfl_xor(sum, 32);
        const float inv = 1.f / sum;
        #pragma unroll
        for (int mj = 0; mj < 4; ++mj) {
            union { short h4[4]; uint2 u2; } pk;
            #pragma unroll
            for (int r = 0; r < 4; ++r) pk.h4[r] = f2bs(acc[mj][ni][r] * inv);
            int off = (i << 7) + ((mj * 16 + g * 4) << 1);
            off ^= (i & 7) << 4;
            *(uint2*)(ps + off) = pk.u2;
        }
    }

    // PV: acc2[md][ni] = O^T[d][i]
    f32x4 acc2[2][4];
    #pragma unroll
    for (int i = 0; i < 2; ++i)
        #pragma unroll
        for (int j = 0; j < 4; ++j) acc2[i][j] = (f32x4)0.0f;
    #pragma unroll
    for (int kk = 0; kk < 2; ++kk) {
        bf16x8 aV[2], bP[4];
        #pragma unroll
        for (int md = 0; md < 2; ++md) {
            const int d = md * 16 + li;
            int off = (d << 7) + kk * 64 + g * 16;
            off ^= (d & 7) << 4;
            aV[md] = *(const bf16x8*)(vt + off);
        }
        #pragma unroll
        for (int ni = 0; ni < 4; ++ni) {
            const int i = ni * 16 + li;
            int off = (i << 7) + kk * 64 + g * 16;
            off ^= (i & 7) << 4;
            bP[ni] = *(const bf16x8*)(ps + off);
        }
        #pragma unroll
        for (int md = 0; md < 2; ++md)
            #pragma unroll
            for (int ni = 0; ni < 4; ++ni)
                acc2[md][ni] = __builtin_amdgcn_mfma_f32_16x16x32_bf16(
                    aV[md], bP[ni], acc2[md][ni], 0, 0, 0);
    }

    // store O[i][d]
    const size_t obase = (size_t)w * 49 * 384 + h * 32;
    #pragma unroll
    for (int ni = 0; ni < 4; ++ni) {
        const int i = ni * 16 + li;
        if (i < 49) {
            #pragma unroll
            for (int md = 0; md < 2; ++md) {
                const int d0 = md * 16 + g * 4;
                union { short h4[4]; uint2 u2; } pk;
                #pragma unroll
                for (int r = 0; r < 4; ++r) pk.h4[r] = f2bs(acc2[md][ni][r]);
                *(uint2*)&o[obase + (size_t)i * 384 + d0] = pk.u2;
            }
        }
    }
}

// ---------------------------------------------------------------------------
extern "C" void kernel_launch(void* const* d_in, const int* in_sizes, int n_in,
                              void* d_out, int out_size, void* d_ws, size_t ws_size,
                              hipStream_t stream) {
    const float* x      = (const float*)d_in[0];
    const float* n1w    = (const float*)d_in[1];
    const float* n1b    = (const float*)d_in[2];
    const float* qkv_w  = (const float*)d_in[3];
    const float* qkv_b  = (const float*)d_in[4];
    const float* table  = (const float*)d_in[5];
    const float* proj_w = (const float*)d_in[6];
    const float* proj_b = (const float*)d_in[7];
    const float* n2w    = (const float*)d_in[8];
    const float* n2b    = (const float*)d_in[9];
    const float* fc1_w  = (const float*)d_in[10];
    const float* fc1_b  = (const float*)d_in[11];
    const float* fc2_w  = (const float*)d_in[12];
    const float* fc2_b  = (const float*)d_in[13];
    float* out = (float*)d_out;

    char* ws = (char*)d_ws;
    bf16* buf0 = (bf16*)ws;                              // TOK*384 bf16
    bf16* buf1 = (bf16*)(ws + 77070336);                 // qkv / hid
    bf16* wb   = (bf16*)(ws + 77070336 + 308281344);     // bf16 weights

    convert_w_kernel<<<1728, 256, 0, stream>>>(qkv_w, proj_w, fc1_w, fc2_w, wb);
    // 1) LN1 + roll + window partition -> buf0
    ln_kernel<true><<<TOK / 4, 256, 0, stream>>>(x, n1w, n1b, buf0);
    // 2) QKV GEMM -> buf1 (q|k|v, head-major)
    gemm_bt<0><<<784 * 9, 256, 0, stream>>>(buf0, wb, qkv_b,
                                            buf1, nullptr, nullptr, 384, 9);
    // 3) MFMA windowed attention -> buf0
    attn_mfma<<<2048 * 12 / 4, 256, 0, stream>>>(buf1, buf1 + QKV_SEG,
                                                 buf1 + 2 * QKV_SEG, table, buf0);
    // 4) proj GEMM + reverse/roll + residual -> out
    gemm_bt<1><<<784 * 3, 256, 0, stream>>>(buf0, wb + 442368, proj_b,
                                            nullptr, out, x, 384, 3);
    // 5) LN2(y) -> buf0
    ln_kernel<false><<<TOK / 4, 256, 0, stream>>>(out, n2w, n2b, buf0);
    // 6) fc1 + GELU -> buf1
    gemm_bt<2><<<784 * 12, 256, 0, stream>>>(buf0, wb + 589824, fc1_b,
                                             buf1, nullptr, nullptr, 384, 12);
    // 7) fc2 + residual (in-place on out)
    gemm_bt<3><<<784 * 3, 256, 0, stream>>>(buf1, wb + 1179648, fc2_b,
                                            nullptr, out, out, 1536, 3);
}

// Round 4
// 962.873 us; speedup vs baseline: 1.3040x; 1.0489x over previous
//
#include <hip/hip_runtime.h>
#include <hip/hip_bf16.h>
#include <math.h>

using bf16 = __hip_bfloat16;
typedef short bf16x8 __attribute__((ext_vector_type(8)));
typedef float f32x4 __attribute__((ext_vector_type(4)));

static constexpr int  TOK     = 100352;     // 32*56*56 tokens
static constexpr long QKV_SEG = 38535168L;  // TOK*384 elements per q/k/v segment

__device__ __forceinline__ float bf2f(short u) {
    return __uint_as_float(((unsigned)(unsigned short)u) << 16);
}
__device__ __forceinline__ short f2bs(float x) {
    union { bf16 b; short s; } u; u.b = __float2bfloat16(x); return u.s;
}
// async global->LDS, 16B per lane. LDS dest must be uniform base + lane*16.
__device__ __forceinline__ void gload16(const void* g, void* l) {
    __builtin_amdgcn_global_load_lds(
        (const __attribute__((address_space(1))) unsigned int*)g,
        (__attribute__((address_space(3))) unsigned int*)l, 16, 0, 0);
}
// tanh-form GELU: x * sigmoid(1.5957691x + 0.071354816x^3); max |err| ~1e-3
__device__ __forceinline__ float gelu_fast(float x) {
    const float x2 = x * x;
    const float t1 = x * x2;
    const float y  = fmaf(0.071354816222f, t1, 1.5957691216f * x);
    const float e  = __expf(-y);
    return x * __frcp_rn(1.f + e);
}

// ---------------------------------------------------------------------------
// Pre-convert all fp32 weights to bf16 (once per launch, ~7MB traffic).
// layout: qkv[0,442368) proj[442368,589824) fc1[589824,1179648) fc2[1179648,1769472)
// ---------------------------------------------------------------------------
__global__ __launch_bounds__(256)
void convert_w_kernel(const float* __restrict__ qkv_w, const float* __restrict__ proj_w,
                      const float* __restrict__ fc1_w, const float* __restrict__ fc2_w,
                      bf16* __restrict__ out)
{
    const int i4 = (blockIdx.x * 256 + threadIdx.x) * 4;
    if (i4 >= 1769472) return;
    const float* src; int off;
    if (i4 < 442368)       { src = qkv_w;  off = i4; }
    else if (i4 < 589824)  { src = proj_w; off = i4 - 442368; }
    else if (i4 < 1179648) { src = fc1_w;  off = i4 - 589824; }
    else                   { src = fc2_w;  off = i4 - 1179648; }
    const float4 v = *(const float4*)&src[off];
    out[i4+0] = __float2bfloat16(v.x);
    out[i4+1] = __float2bfloat16(v.y);
    out[i4+2] = __float2bfloat16(v.z);
    out[i4+3] = __float2bfloat16(v.w);
}

// ---------------------------------------------------------------------------
// LayerNorm over C=384, one wave per token. WINDOWED: dst order is
// (b, window, intra-window) after roll(-3,-3); source is original x.
// ---------------------------------------------------------------------------
template<bool WINDOWED>
__global__ __launch_bounds__(256)
void ln_kernel(const float* __restrict__ x, const float* __restrict__ gw,
               const float* __restrict__ gb, bf16* __restrict__ out)
{
    const int wave = threadIdx.x >> 6;
    const int lane = threadIdx.x & 63;
    const long t = (long)blockIdx.x * 4 + wave;
    size_t src;
    if (WINDOWED) {
        int bb = (int)(t / 3136); int rem = (int)(t - (long)bb * 3136);
        int wIdx = rem / 49;      int n = rem - wIdx * 49;
        int wh = wIdx >> 3, ww = wIdx & 7;
        int yi = n / 7,     xi = n - yi * 7;
        int r = wh * 7 + yi + 3; if (r >= 56) r -= 56;
        int c = ww * 7 + xi + 3; if (c >= 56) c -= 56;
        src = ((size_t)bb * 3136 + (size_t)r * 56 + c) * 384;
    } else {
        src = (size_t)t * 384;
    }
    float v[6]; float s = 0.f, sq = 0.f;
    #pragma unroll
    for (int kk = 0; kk < 6; ++kk) {
        v[kk] = x[src + lane + 64 * kk];
        s += v[kk]; sq += v[kk] * v[kk];
    }
    #pragma unroll
    for (int o = 32; o > 0; o >>= 1) { s += __shfl_xor(s, o); sq += __shfl_xor(sq, o); }
    const float m   = s * (1.f / 384.f);
    const float var = sq * (1.f / 384.f) - m * m;
    const float rs  = rsqrtf(var + 1e-5f);
    #pragma unroll
    for (int kk = 0; kk < 6; ++kk) {
        int ch = lane + 64 * kk;
        out[(size_t)t * 384 + ch] = __float2bfloat16((v[kk] - m) * rs * gw[ch] + gb[ch]);
    }
}

// ---------------------------------------------------------------------------
// GEMM: C[M,N] = A[M,K](bf16) @ W[N,K]^T(bf16) + bias.
// 128x128 tile, BK=64, 4 waves 2x2, double-buffered global_load_lds staging
// (one barrier per K-step, stage-before-compute), T2 XOR swizzle via
// pre-swizzled GLOBAL source + swizzled ds_read (both-sides involution).
// MFMA operands swapped -> lane holds 4 consecutive output features.
// ---------------------------------------------------------------------------
template<int MODE>
__global__ __launch_bounds__(256)
void gemm_bt(const bf16* __restrict__ A, const bf16* __restrict__ W,
             const float* __restrict__ bias, bf16* __restrict__ outb,
             float* __restrict__ outf, const float* __restrict__ resid,
             int K, int tilesN)
{
    __shared__ bf16 As[2][128 * 64];
    __shared__ bf16 Bs[2][128 * 64];
    const int nwg = gridDim.x;
    const int b0  = blockIdx.x;
    const int swz = (b0 & 7) * (nwg >> 3) + (b0 >> 3);
    const int tm = swz / tilesN;
    const int tn = swz - tm * tilesN;
    const int tid  = threadIdx.x;
    const int lane = tid & 63;
    const int wid  = tid >> 6;
    const int wr = (wid >> 1) * 64;   // M offset of wave tile
    const int wc = (wid & 1) * 64;    // N offset of wave tile
    const int sr = tid >> 3;          // staging row 0..31
    const int sc = (tid & 7) * 8;     // staging LDS col 0..56 step 8
    const int scs = sc ^ ((sr & 7) << 3);   // pre-swizzled SOURCE col

    f32x4 acc[4][4];                  // [nf][mf]
    #pragma unroll
    for (int i = 0; i < 4; ++i)
        #pragma unroll
        for (int j = 0; j < 4; ++j) acc[i][j] = (f32x4)0.0f;

    const long am0 = (long)tm * 128;
    const int  bn0 = tn * 128;
    const bf16* Ab = A + am0 * K + scs;        // + row*K + k0
    const bf16* Wb = W + (long)bn0 * K + scs;

    #define STAGE(bufi, k0_) do {                                          \
        _Pragma("unroll")                                                   \
        for (int p = 0; p < 4; ++p) {                                       \
            const int row_ = p * 32 + sr;                                   \
            gload16(&Ab[(size_t)row_ * K + (k0_)], &As[bufi][row_ * 64 + sc]); \
            gload16(&Wb[(size_t)row_ * K + (k0_)], &Bs[bufi][row_ * 64 + sc]); \
        } } while (0)

    const int rophase = (lane & 7) << 3;   // read-side swizzle phase
    const int kbase   = (lane >> 4) * 8;

    #define COMPUTE(bufi) do {                                              \
        _Pragma("unroll")                                                   \
        for (int kk = 0; kk < 2; ++kk) {                                    \
            const int kofs = (kk * 32 + kbase) ^ rophase;                   \
            bf16x8 aF[4], bF[4];                                            \
            _Pragma("unroll")                                               \
            for (int mi = 0; mi < 4; ++mi)                                  \
                aF[mi] = *(const bf16x8*)&As[bufi][(wr + mi * 16 + (lane & 15)) * 64 + kofs]; \
            _Pragma("unroll")                                               \
            for (int ni = 0; ni < 4; ++ni)                                  \
                bF[ni] = *(const bf16x8*)&Bs[bufi][(wc + ni * 16 + (lane & 15)) * 64 + kofs]; \
            _Pragma("unroll")                                               \
            for (int ni = 0; ni < 4; ++ni)                                  \
                _Pragma("unroll")                                           \
                for (int mi = 0; mi < 4; ++mi)                              \
                    acc[ni][mi] = __builtin_amdgcn_mfma_f32_16x16x32_bf16(  \
                        bF[ni], aF[mi], acc[ni][mi], 0, 0, 0);              \
        } } while (0)

    // 2-phase pipeline: stage t+1 while computing t; ONE barrier per K-step.
    STAGE(0, 0);
    __syncthreads();
    int cur = 0;
    const int nsteps = K >> 6;
    for (int t = 0; t < nsteps - 1; ++t) {
        STAGE(cur ^ 1, (t + 1) << 6);
        __builtin_amdgcn_sched_barrier(0);   // keep prefetch issue ahead of compute
        COMPUTE(cur);
        __syncthreads();                     // drains vmcnt AFTER compute phase
        cur ^= 1;
    }
    COMPUTE(cur);
    #undef STAGE
    #undef COMPUTE

    // epilogue: lane holds features gn0..gn0+3 at token gm
    #pragma unroll
    for (int nf = 0; nf < 4; ++nf) {
        const int gn0 = bn0 + wc + nf * 16 + ((lane >> 4) << 2);  // 4-aligned
        const float4 bv = *(const float4*)&bias[gn0];
        int s3 = 0, hh = 0, d0 = 0;
        if (MODE == 0) {
            s3 = gn0 / 384; const int rem = gn0 - s3 * 384;
            hh = rem >> 5; d0 = rem & 31;
        }
        #pragma unroll
        for (int mf = 0; mf < 4; ++mf) {
            const long gm = am0 + wr + mf * 16 + (lane & 15);
            float vals[4];
            #pragma unroll
            for (int r = 0; r < 4; ++r) vals[r] = acc[nf][mf][r] + ((const float*)&bv)[r];

            if (MODE == 0) {
                long wwi = gm / 49; int ntok = (int)(gm - wwi * 49);
                size_t dst = (size_t)s3 * QKV_SEG
                           + ((size_t)(wwi * 12 + hh) * 49 + ntok) * 32 + d0;
                union { short h4[4]; uint2 u2; } pk;
                if (s3 == 0) {
                    #pragma unroll
                    for (int r = 0; r < 4; ++r)
                        pk.h4[r] = f2bs(vals[r] * 0.17677669529663687f);
                } else {
                    #pragma unroll
                    for (int r = 0; r < 4; ++r) pk.h4[r] = f2bs(vals[r]);
                }
                *(uint2*)&outb[dst] = pk.u2;
            } else if (MODE == 1) {
                int bb = (int)(gm / 3136); int rem = (int)(gm - (long)bb * 3136);
                int wIdx = rem / 49; int n = rem - wIdx * 49;
                int wh = wIdx >> 3, ww2 = wIdx & 7;
                int yi = n / 7,     xi = n - yi * 7;
                int rr = wh * 7 + yi + 3; if (rr >= 56) rr -= 56;
                int cc = ww2 * 7 + xi + 3; if (cc >= 56) cc -= 56;
                size_t dst = ((size_t)bb * 3136 + (size_t)rr * 56 + cc) * 384 + gn0;
                const float4 rv = *(const float4*)&resid[dst];
                float4 ov;
                ov.x = rv.x + vals[0]; ov.y = rv.y + vals[1];
                ov.z = rv.z + vals[2]; ov.w = rv.w + vals[3];
                *(float4*)&outf[dst] = ov;
            } else if (MODE == 2) {
                union { short h4[4]; uint2 u2; } pk;
                #pragma unroll
                for (int r = 0; r < 4; ++r) pk.h4[r] = f2bs(gelu_fast(vals[r]));
                *(uint2*)&outb[(size_t)gm * 1536 + gn0] = pk.u2;
            } else {
                size_t dst = (size_t)gm * 384 + gn0;
                const float4 rv = *(const float4*)&resid[dst];
                float4 ov;
                ov.x = rv.x + vals[0]; ov.y = rv.y + vals[1];
                ov.z = rv.z + vals[2]; ov.w = rv.w + vals[3];
                *(float4*)&outf[dst] = ov;
            }
        }
    }
}

// ---------------------------------------------------------------------------
// MFMA windowed attention. 4 waves/block, one (window,head) per wave.
// Swapped QK^T: S^T = mfma(A=K, B=Q) -> lane owns query col i. Softmax:
// 16 in-lane + shfl_xor(16,32). P -> LDS (XOR-swizzled). PV: O^T = mfma(V^T, P).
// ---------------------------------------------------------------------------
__global__ __launch_bounds__(256)
void attn_mfma(const bf16* __restrict__ q, const bf16* __restrict__ k,
               const bf16* __restrict__ v, const float* __restrict__ table,
               bf16* __restrict__ o)
{
    __shared__ bf16  vt_s[4][2048];   // per wave: V^T [32 d][64 j], swizzled
    __shared__ bf16  p_s[4][4096];    // per wave: P   [64 i][64 j], swizzled
    __shared__ float tbl_s[4][169];

    const int tid  = threadIdx.x;
    const int wid  = tid >> 6;
    const int lane = tid & 63;
    const int li = lane & 15, g = lane >> 4;
    const int gwh = blockIdx.x * 4 + wid;       // window*12 + head
    const int w = gwh / 12, h = gwh - w * 12;
    const int wIdx = w & 63;
    const int bh = wIdx >> 3, bw = wIdx & 7;
    const size_t base = (size_t)gwh * 1568;

    char* vt = (char*)vt_s[wid];
    char* ps = (char*)p_s[wid];

    for (int t = lane; t < 169; t += 64) tbl_s[wid][t] = table[t * 12 + h];

    {
        const int4 z = {0, 0, 0, 0};
        #pragma unroll
        for (int t = 0; t < 4; ++t) ((int4*)vt)[t * 64 + lane] = z;
        for (int t = lane; t < 196; t += 64) {
            const int j = t >> 2, d0 = (t & 3) * 8;
            bf16x8 row = *(const bf16x8*)&v[base + (size_t)j * 32 + d0];
            #pragma unroll
            for (int u = 0; u < 8; ++u) {
                const int d = d0 + u;
                int off = (d << 7) + (j << 1);
                off ^= (d & 7) << 4;
                *(short*)(vt + off) = row[u];
            }
        }
    }

    // QK^T (swapped): acc[mj][ni] = S^T[j][i]
    bf16x8 aK[4], bQ[4];
    const int koff = g * 8;
    #pragma unroll
    for (int mj = 0; mj < 4; ++mj)
        aK[mj] = *(const bf16x8*)&k[base + (size_t)(mj * 16 + li) * 32 + koff];
    #pragma unroll
    for (int ni = 0; ni < 4; ++ni)
        bQ[ni] = *(const bf16x8*)&q[base + (size_t)(ni * 16 + li) * 32 + koff];

    f32x4 acc[4][4];
    #pragma unroll
    for (int i = 0; i < 4; ++i)
        #pragma unroll
        for (int j = 0; j < 4; ++j) acc[i][j] = (f32x4)0.0f;
    #pragma unroll
    for (int mj = 0; mj < 4; ++mj)
        #pragma unroll
        for (int ni = 0; ni < 4; ++ni)
            acc[mj][ni] = __builtin_amdgcn_mfma_f32_16x16x32_bf16(
                aK[mj], bQ[ni], acc[mj][ni], 0, 0, 0);

    // softmax over j per query i
    const bool bndH = (bh == 7), bndW = (bw == 7);
    #pragma unroll
    for (int ni = 0; ni < 4; ++ni) {
        const int i = ni * 16 + li;
        const int yi = i / 7, xi = i - yi * 7;
        const int ri = (bndH ? (yi < 4 ? 3 : 6) : 0) + (bndW ? (xi < 4 ? 1 : 2) : 0);
        float mx = -1e30f;
        #pragma unroll
        for (int mj = 0; mj < 4; ++mj)
            #pragma unroll
            for (int r = 0; r < 4; ++r) {
                const int j = mj * 16 + g * 4 + r;
                const int yj = j / 7, xj = j - yj * 7;
                int ridx = (yi - yj + 6) * 13 + (xi - xj + 6);
                ridx = max(0, min(168, ridx));
                float val = acc[mj][ni][r] + tbl_s[wid][ridx];
                const int rj = (bndH ? (yj < 4 ? 3 : 6) : 0) + (bndW ? (xj < 4 ? 1 : 2) : 0);
                if (ri != rj) val -= 100.f;
                if (j >= 49) val = -1e30f;
                acc[mj][ni][r] = val;
                mx = fmaxf(mx, val);
            }
        mx = fmaxf(mx, __shfl_xor(mx, 16));
        mx = fmaxf(mx, __shfl_xor(mx, 32));
        float sum = 0.f;
        #pragma unroll
        for (int mj = 0; mj < 4; ++mj)
            #pragma unroll
            for (int r = 0; r < 4; ++r) {
                const float p = __expf(acc[mj][ni][r] - mx);
                acc[mj][ni][r] = p; sum += p;
            }
        sum += __shfl_xor(sum, 16);
        sum += __shfl_xor(sum, 32);
        const float inv = 1.f / sum;
        #pragma unroll
        for (int mj = 0; mj < 4; ++mj) {
            union { short h4[4]; uint2 u2; } pk;
            #pragma unroll
            for (int r = 0; r < 4; ++r) pk.h4[r] = f2bs(acc[mj][ni][r] * inv);
            int off = (i << 7) + ((mj * 16 + g * 4) << 1);
            off ^= (i & 7) << 4;
            *(uint2*)(ps + off) = pk.u2;
        }
    }

    // PV: acc2[md][ni] = O^T[d][i]
    f32x4 acc2[2][4];
    #pragma unroll
    for (int i = 0; i < 2; ++i)
        #pragma unroll
        for (int j = 0; j < 4; ++j) acc2[i][j] = (f32x4)0.0f;
    #pragma unroll
    for (int kk = 0; kk < 2; ++kk) {
        bf16x8 aV[2], bP[4];
        #pragma unroll
        for (int md = 0; md < 2; ++md) {
            const int d = md * 16 + li;
            int off = (d << 7) + kk * 64 + g * 16;
            off ^= (d & 7) << 4;
            aV[md] = *(const bf16x8*)(vt + off);
        }
        #pragma unroll
        for (int ni = 0; ni < 4; ++ni) {
            const int i = ni * 16 + li;
            int off = (i << 7) + kk * 64 + g * 16;
            off ^= (i & 7) << 4;
            bP[ni] = *(const bf16x8*)(ps + off);
        }
        #pragma unroll
        for (int md = 0; md < 2; ++md)
            #pragma unroll
            for (int ni = 0; ni < 4; ++ni)
                acc2[md][ni] = __builtin_amdgcn_mfma_f32_16x16x32_bf16(
                    aV[md], bP[ni], acc2[md][ni], 0, 0, 0);
    }

    // store O[i][d]
    const size_t obase = (size_t)w * 49 * 384 + h * 32;
    #pragma unroll
    for (int ni = 0; ni < 4; ++ni) {
        const int i = ni * 16 + li;
        if (i < 49) {
            #pragma unroll
            for (int md = 0; md < 2; ++md) {
                const int d0 = md * 16 + g * 4;
                union { short h4[4]; uint2 u2; } pk;
                #pragma unroll
                for (int r = 0; r < 4; ++r) pk.h4[r] = f2bs(acc2[md][ni][r]);
                *(uint2*)&o[obase + (size_t)i * 384 + d0] = pk.u2;
            }
        }
    }
}

// ---------------------------------------------------------------------------
extern "C" void kernel_launch(void* const* d_in, const int* in_sizes, int n_in,
                              void* d_out, int out_size, void* d_ws, size_t ws_size,
                              hipStream_t stream) {
    const float* x      = (const float*)d_in[0];
    const float* n1w    = (const float*)d_in[1];
    const float* n1b    = (const float*)d_in[2];
    const float* qkv_w  = (const float*)d_in[3];
    const float* qkv_b  = (const float*)d_in[4];
    const float* table  = (const float*)d_in[5];
    const float* proj_w = (const float*)d_in[6];
    const float* proj_b = (const float*)d_in[7];
    const float* n2w    = (const float*)d_in[8];
    const float* n2b    = (const float*)d_in[9];
    const float* fc1_w  = (const float*)d_in[10];
    const float* fc1_b  = (const float*)d_in[11];
    const float* fc2_w  = (const float*)d_in[12];
    const float* fc2_b  = (const float*)d_in[13];
    float* out = (float*)d_out;

    char* ws = (char*)d_ws;
    bf16* buf0 = (bf16*)ws;                              // TOK*384 bf16
    bf16* buf1 = (bf16*)(ws + 77070336);                 // qkv / hid
    bf16* wb   = (bf16*)(ws + 77070336 + 308281344);     // bf16 weights

    convert_w_kernel<<<1728, 256, 0, stream>>>(qkv_w, proj_w, fc1_w, fc2_w, wb);
    // 1) LN1 + roll + window partition -> buf0
    ln_kernel<true><<<TOK / 4, 256, 0, stream>>>(x, n1w, n1b, buf0);
    // 2) QKV GEMM -> buf1 (q|k|v, head-major)
    gemm_bt<0><<<784 * 9, 256, 0, stream>>>(buf0, wb, qkv_b,
                                            buf1, nullptr, nullptr, 384, 9);
    // 3) MFMA windowed attention -> buf0
    attn_mfma<<<2048 * 12 / 4, 256, 0, stream>>>(buf1, buf1 + QKV_SEG,
                                                 buf1 + 2 * QKV_SEG, table, buf0);
    // 4) proj GEMM + reverse/roll + residual -> out
    gemm_bt<1><<<784 * 3, 256, 0, stream>>>(buf0, wb + 442368, proj_b,
                                            nullptr, out, x, 384, 3);
    // 5) LN2(y) -> buf0
    ln_kernel<false><<<TOK / 4, 256, 0, stream>>>(out, n2w, n2b, buf0);
    // 6) fc1 + GELU -> buf1
    gemm_bt<2><<<784 * 12, 256, 0, stream>>>(buf0, wb + 589824, fc1_b,
                                             buf1, nullptr, nullptr, 384, 12);
    // 7) fc2 + residual (in-place on out)
    gemm_bt<3><<<784 * 3, 256, 0, stream>>>(buf1, wb + 1179648, fc2_b,
                                            nullptr, out, out, 1536, 3);
}

// Round 5
// 932.160 us; speedup vs baseline: 1.3469x; 1.0329x over previous
//
#include <hip/hip_runtime.h>
#include <hip/hip_bf16.h>
#include <math.h>

using bf16 = __hip_bfloat16;
typedef short bf16x8 __attribute__((ext_vector_type(8)));
typedef float f32x4 __attribute__((ext_vector_type(4)));

static constexpr int  TOK     = 100352;     // 32*56*56 tokens
static constexpr long QKV_SEG = 38535168L;  // TOK*384 elements per q/k/v segment

__device__ __forceinline__ float bf2f(short u) {
    return __uint_as_float(((unsigned)(unsigned short)u) << 16);
}
__device__ __forceinline__ short f2bs(float x) {
    union { bf16 b; short s; } u; u.b = __float2bfloat16(x); return u.s;
}
// async global->LDS, 16B per lane. LDS dest must be uniform base + lane*16.
__device__ __forceinline__ void gload16(const void* g, void* l) {
    __builtin_amdgcn_global_load_lds(
        (const __attribute__((address_space(1))) unsigned int*)g,
        (__attribute__((address_space(3))) unsigned int*)l, 16, 0, 0);
}
// tanh-form GELU: x * sigmoid(1.5957691x + 0.071354816x^3); max |err| ~1e-3
__device__ __forceinline__ float gelu_fast(float x) {
    const float x2 = x * x;
    const float t1 = x * x2;
    const float y  = fmaf(0.071354816222f, t1, 1.5957691216f * x);
    const float e  = __expf(-y);
    return x * __frcp_rn(1.f + e);
}

// ---------------------------------------------------------------------------
// Pre-convert all fp32 weights to bf16 (once per launch, ~7MB traffic).
// layout: qkv[0,442368) proj[442368,589824) fc1[589824,1179648) fc2[1179648,1769472)
// ---------------------------------------------------------------------------
__global__ __launch_bounds__(256)
void convert_w_kernel(const float* __restrict__ qkv_w, const float* __restrict__ proj_w,
                      const float* __restrict__ fc1_w, const float* __restrict__ fc2_w,
                      bf16* __restrict__ out)
{
    const int i4 = (blockIdx.x * 256 + threadIdx.x) * 4;
    if (i4 >= 1769472) return;
    const float* src; int off;
    if (i4 < 442368)       { src = qkv_w;  off = i4; }
    else if (i4 < 589824)  { src = proj_w; off = i4 - 442368; }
    else if (i4 < 1179648) { src = fc1_w;  off = i4 - 589824; }
    else                   { src = fc2_w;  off = i4 - 1179648; }
    const float4 v = *(const float4*)&src[off];
    out[i4+0] = __float2bfloat16(v.x);
    out[i4+1] = __float2bfloat16(v.y);
    out[i4+2] = __float2bfloat16(v.z);
    out[i4+3] = __float2bfloat16(v.w);
}

// ---------------------------------------------------------------------------
// LayerNorm over C=384, one wave per token. WINDOWED: dst order is
// (b, window, intra-window) after roll(-3,-3); source is original x.
// ---------------------------------------------------------------------------
template<bool WINDOWED>
__global__ __launch_bounds__(256)
void ln_kernel(const float* __restrict__ x, const float* __restrict__ gw,
               const float* __restrict__ gb, bf16* __restrict__ out)
{
    const int wave = threadIdx.x >> 6;
    const int lane = threadIdx.x & 63;
    const long t = (long)blockIdx.x * 4 + wave;
    size_t src;
    if (WINDOWED) {
        int bb = (int)(t / 3136); int rem = (int)(t - (long)bb * 3136);
        int wIdx = rem / 49;      int n = rem - wIdx * 49;
        int wh = wIdx >> 3, ww = wIdx & 7;
        int yi = n / 7,     xi = n - yi * 7;
        int r = wh * 7 + yi + 3; if (r >= 56) r -= 56;
        int c = ww * 7 + xi + 3; if (c >= 56) c -= 56;
        src = ((size_t)bb * 3136 + (size_t)r * 56 + c) * 384;
    } else {
        src = (size_t)t * 384;
    }
    float v[6]; float s = 0.f, sq = 0.f;
    #pragma unroll
    for (int kk = 0; kk < 6; ++kk) {
        v[kk] = x[src + lane + 64 * kk];
        s += v[kk]; sq += v[kk] * v[kk];
    }
    #pragma unroll
    for (int o = 32; o > 0; o >>= 1) { s += __shfl_xor(s, o); sq += __shfl_xor(sq, o); }
    const float m   = s * (1.f / 384.f);
    const float var = sq * (1.f / 384.f) - m * m;
    const float rs  = rsqrtf(var + 1e-5f);
    #pragma unroll
    for (int kk = 0; kk < 6; ++kk) {
        int ch = lane + 64 * kk;
        out[(size_t)t * 384 + ch] = __float2bfloat16((v[kk] - m) * rs * gw[ch] + gb[ch]);
    }
}

// ---------------------------------------------------------------------------
// GEMM: C[M,N] = A[M,K](bf16) @ W[N,K]^T(bf16) + bias.
// 128x128 tile, BK=64, 4 waves 2x2, double-buffered global_load_lds staging.
// T4 counted-vmcnt pipeline: prologue stages steps 0,1; per K-step wait
// vmcnt(8) (older buffer only) -> raw s_barrier -> MFMA -> lgkmcnt(0)+barrier
// -> stage step t+2. Prefetch loads stay in flight ACROSS barriers; no
// vmcnt(0) drain in the main loop. T2 XOR swizzle (both-sides involution).
// MFMA operands swapped -> lane holds 4 consecutive output features.
// ---------------------------------------------------------------------------
template<int MODE>
__global__ __launch_bounds__(256)
void gemm_bt(const bf16* __restrict__ A, const bf16* __restrict__ W,
             const float* __restrict__ bias, bf16* __restrict__ outb,
             float* __restrict__ outf, const float* __restrict__ resid,
             int K, int tilesN)
{
    __shared__ bf16 As[2][128 * 64];
    __shared__ bf16 Bs[2][128 * 64];
    const int nwg = gridDim.x;
    const int b0  = blockIdx.x;
    const int swz = (b0 & 7) * (nwg >> 3) + (b0 >> 3);
    const int tm = swz / tilesN;
    const int tn = swz - tm * tilesN;
    const int tid  = threadIdx.x;
    const int lane = tid & 63;
    const int wid  = tid >> 6;
    const int wr = (wid >> 1) * 64;   // M offset of wave tile
    const int wc = (wid & 1) * 64;    // N offset of wave tile
    const int sr = tid >> 3;          // staging row 0..31
    const int sc = (tid & 7) * 8;     // staging LDS col 0..56 step 8
    const int scs = sc ^ ((sr & 7) << 3);   // pre-swizzled SOURCE col

    f32x4 acc[4][4];                  // [nf][mf]
    #pragma unroll
    for (int i = 0; i < 4; ++i)
        #pragma unroll
        for (int j = 0; j < 4; ++j) acc[i][j] = (f32x4)0.0f;

    const long am0 = (long)tm * 128;
    const int  bn0 = tn * 128;
    const bf16* Ab = A + am0 * K + scs;        // + row*K + k0
    const bf16* Wb = W + (long)bn0 * K + scs;

    #define STAGE(bufi, k0_) do {                                          \
        _Pragma("unroll")                                                   \
        for (int p = 0; p < 4; ++p) {                                       \
            const int row_ = p * 32 + sr;                                   \
            gload16(&Ab[(size_t)row_ * K + (k0_)], &As[bufi][row_ * 64 + sc]); \
            gload16(&Wb[(size_t)row_ * K + (k0_)], &Bs[bufi][row_ * 64 + sc]); \
        } } while (0)

    const int rophase = (lane & 7) << 3;   // read-side swizzle phase
    const int kbase   = (lane >> 4) * 8;

    #define COMPUTE(bufi) do {                                              \
        _Pragma("unroll")                                                   \
        for (int kk = 0; kk < 2; ++kk) {                                    \
            const int kofs = (kk * 32 + kbase) ^ rophase;                   \
            bf16x8 aF[4], bF[4];                                            \
            _Pragma("unroll")                                               \
            for (int mi = 0; mi < 4; ++mi)                                  \
                aF[mi] = *(const bf16x8*)&As[bufi][(wr + mi * 16 + (lane & 15)) * 64 + kofs]; \
            _Pragma("unroll")                                               \
            for (int ni = 0; ni < 4; ++ni)                                  \
                bF[ni] = *(const bf16x8*)&Bs[bufi][(wc + ni * 16 + (lane & 15)) * 64 + kofs]; \
            _Pragma("unroll")                                               \
            for (int ni = 0; ni < 4; ++ni)                                  \
                _Pragma("unroll")                                           \
                for (int mi = 0; mi < 4; ++mi)                              \
                    acc[ni][mi] = __builtin_amdgcn_mfma_f32_16x16x32_bf16(  \
                        bF[ni], aF[mi], acc[ni][mi], 0, 0, 0);              \
        } } while (0)

    // ---- counted-vmcnt 2-buffer pipeline (T4): never drain vmcnt to 0 ----
    const int nsteps = K >> 6;          // >= 2 for all our shapes
    STAGE(0, 0);
    STAGE(1, 64);
    int cur = 0;
    for (int t = 0; t < nsteps - 1; ++t) {
        // wait ONLY for buf[cur]'s 8 loads (8 newer stay in flight)
        asm volatile("s_waitcnt vmcnt(8)" ::: "memory");
        __builtin_amdgcn_s_barrier();           // all waves' buf[cur] ready
        COMPUTE(cur);
        asm volatile("s_waitcnt lgkmcnt(0)" ::: "memory");
        __builtin_amdgcn_s_barrier();           // all waves done READING buf[cur]
        if (t + 2 < nsteps) STAGE(cur, (t + 2) << 6);
        cur ^= 1;
    }
    asm volatile("s_waitcnt vmcnt(0)" ::: "memory");
    __builtin_amdgcn_s_barrier();
    COMPUTE(cur);
    #undef STAGE
    #undef COMPUTE

    // epilogue: lane holds features gn0..gn0+3 at token gm
    #pragma unroll
    for (int nf = 0; nf < 4; ++nf) {
        const int gn0 = bn0 + wc + nf * 16 + ((lane >> 4) << 2);  // 4-aligned
        const float4 bv = *(const float4*)&bias[gn0];
        int s3 = 0, hh = 0, d0 = 0;
        if (MODE == 0) {
            s3 = gn0 / 384; const int rem = gn0 - s3 * 384;
            hh = rem >> 5; d0 = rem & 31;
        }
        #pragma unroll
        for (int mf = 0; mf < 4; ++mf) {
            const long gm = am0 + wr + mf * 16 + (lane & 15);
            float vals[4];
            #pragma unroll
            for (int r = 0; r < 4; ++r) vals[r] = acc[nf][mf][r] + ((const float*)&bv)[r];

            if (MODE == 0) {
                long wwi = gm / 49; int ntok = (int)(gm - wwi * 49);
                size_t dst = (size_t)s3 * QKV_SEG
                           + ((size_t)(wwi * 12 + hh) * 49 + ntok) * 32 + d0;
                union { short h4[4]; uint2 u2; } pk;
                if (s3 == 0) {
                    #pragma unroll
                    for (int r = 0; r < 4; ++r)
                        pk.h4[r] = f2bs(vals[r] * 0.17677669529663687f);
                } else {
                    #pragma unroll
                    for (int r = 0; r < 4; ++r) pk.h4[r] = f2bs(vals[r]);
                }
                *(uint2*)&outb[dst] = pk.u2;
            } else if (MODE == 1) {
                int bb = (int)(gm / 3136); int rem = (int)(gm - (long)bb * 3136);
                int wIdx = rem / 49; int n = rem - wIdx * 49;
                int wh = wIdx >> 3, ww2 = wIdx & 7;
                int yi = n / 7,     xi = n - yi * 7;
                int rr = wh * 7 + yi + 3; if (rr >= 56) rr -= 56;
                int cc = ww2 * 7 + xi + 3; if (cc >= 56) cc -= 56;
                size_t dst = ((size_t)bb * 3136 + (size_t)rr * 56 + cc) * 384 + gn0;
                const float4 rv = *(const float4*)&resid[dst];
                float4 ov;
                ov.x = rv.x + vals[0]; ov.y = rv.y + vals[1];
                ov.z = rv.z + vals[2]; ov.w = rv.w + vals[3];
                *(float4*)&outf[dst] = ov;
            } else if (MODE == 2) {
                union { short h4[4]; uint2 u2; } pk;
                #pragma unroll
                for (int r = 0; r < 4; ++r) pk.h4[r] = f2bs(gelu_fast(vals[r]));
                *(uint2*)&outb[(size_t)gm * 1536 + gn0] = pk.u2;
            } else {
                size_t dst = (size_t)gm * 384 + gn0;
                const float4 rv = *(const float4*)&resid[dst];
                float4 ov;
                ov.x = rv.x + vals[0]; ov.y = rv.y + vals[1];
                ov.z = rv.z + vals[2]; ov.w = rv.w + vals[3];
                *(float4*)&outf[dst] = ov;
            }
        }
    }
}

// ---------------------------------------------------------------------------
// MFMA windowed attention. 4 waves/block, one (window,head) per wave.
// Swapped QK^T: S^T = mfma(A=K, B=Q) -> lane owns query col i. Softmax:
// 16 in-lane + shfl_xor(16,32). P -> LDS (XOR-swizzled). PV: O^T = mfma(V^T, P).
// ---------------------------------------------------------------------------
__global__ __launch_bounds__(256)
void attn_mfma(const bf16* __restrict__ q, const bf16* __restrict__ k,
               const bf16* __restrict__ v, const float* __restrict__ table,
               bf16* __restrict__ o)
{
    __shared__ bf16  vt_s[4][2048];   // per wave: V^T [32 d][64 j], swizzled
    __shared__ bf16  p_s[4][4096];    // per wave: P   [64 i][64 j], swizzled
    __shared__ float tbl_s[4][169];

    const int tid  = threadIdx.x;
    const int wid  = tid >> 6;
    const int lane = tid & 63;
    const int li = lane & 15, g = lane >> 4;
    const int gwh = blockIdx.x * 4 + wid;       // window*12 + head
    const int w = gwh / 12, h = gwh - w * 12;
    const int wIdx = w & 63;
    const int bh = wIdx >> 3, bw = wIdx & 7;
    const size_t base = (size_t)gwh * 1568;

    char* vt = (char*)vt_s[wid];
    char* ps = (char*)p_s[wid];

    for (int t = lane; t < 169; t += 64) tbl_s[wid][t] = table[t * 12 + h];

    {
        const int4 z = {0, 0, 0, 0};
        #pragma unroll
        for (int t = 0; t < 4; ++t) ((int4*)vt)[t * 64 + lane] = z;
        for (int t = lane; t < 196; t += 64) {
            const int j = t >> 2, d0 = (t & 3) * 8;
            bf16x8 row = *(const bf16x8*)&v[base + (size_t)j * 32 + d0];
            #pragma unroll
            for (int u = 0; u < 8; ++u) {
                const int d = d0 + u;
                int off = (d << 7) + (j << 1);
                off ^= (d & 7) << 4;
                *(short*)(vt + off) = row[u];
            }
        }
    }

    // QK^T (swapped): acc[mj][ni] = S^T[j][i]
    bf16x8 aK[4], bQ[4];
    const int koff = g * 8;
    #pragma unroll
    for (int mj = 0; mj < 4; ++mj)
        aK[mj] = *(const bf16x8*)&k[base + (size_t)(mj * 16 + li) * 32 + koff];
    #pragma unroll
    for (int ni = 0; ni < 4; ++ni)
        bQ[ni] = *(const bf16x8*)&q[base + (size_t)(ni * 16 + li) * 32 + koff];

    f32x4 acc[4][4];
    #pragma unroll
    for (int i = 0; i < 4; ++i)
        #pragma unroll
        for (int j = 0; j < 4; ++j) acc[i][j] = (f32x4)0.0f;
    #pragma unroll
    for (int mj = 0; mj < 4; ++mj)
        #pragma unroll
        for (int ni = 0; ni < 4; ++ni)
            acc[mj][ni] = __builtin_amdgcn_mfma_f32_16x16x32_bf16(
                aK[mj], bQ[ni], acc[mj][ni], 0, 0, 0);

    // softmax over j per query i
    const bool bndH = (bh == 7), bndW = (bw == 7);
    #pragma unroll
    for (int ni = 0; ni < 4; ++ni) {
        const int i = ni * 16 + li;
        const int yi = i / 7, xi = i - yi * 7;
        const int ri = (bndH ? (yi < 4 ? 3 : 6) : 0) + (bndW ? (xi < 4 ? 1 : 2) : 0);
        float mx = -1e30f;
        #pragma unroll
        for (int mj = 0; mj < 4; ++mj)
            #pragma unroll
            for (int r = 0; r < 4; ++r) {
                const int j = mj * 16 + g * 4 + r;
                const int yj = j / 7, xj = j - yj * 7;
                int ridx = (yi - yj + 6) * 13 + (xi - xj + 6);
                ridx = max(0, min(168, ridx));
                float val = acc[mj][ni][r] + tbl_s[wid][ridx];
                const int rj = (bndH ? (yj < 4 ? 3 : 6) : 0) + (bndW ? (xj < 4 ? 1 : 2) : 0);
                if (ri != rj) val -= 100.f;
                if (j >= 49) val = -1e30f;
                acc[mj][ni][r] = val;
                mx = fmaxf(mx, val);
            }
        mx = fmaxf(mx, __shfl_xor(mx, 16));
        mx = fmaxf(mx, __shfl_xor(mx, 32));
        float sum = 0.f;
        #pragma unroll
        for (int mj = 0; mj < 4; ++mj)
            #pragma unroll
            for (int r = 0; r < 4; ++r) {
                const float p = __expf(acc[mj][ni][r] - mx);
                acc[mj][ni][r] = p; sum += p;
            }
        sum += __shfl_xor(sum, 16);
        sum += __shfl_xor(sum, 32);
        const float inv = 1.f / sum;
        #pragma unroll
        for (int mj = 0; mj < 4; ++mj) {
            union { short h4[4]; uint2 u2; } pk;
            #pragma unroll
            for (int r = 0; r < 4; ++r) pk.h4[r] = f2bs(acc[mj][ni][r] * inv);
            int off = (i << 7) + ((mj * 16 + g * 4) << 1);
            off ^= (i & 7) << 4;
            *(uint2*)(ps + off) = pk.u2;
        }
    }

    // PV: acc2[md][ni] = O^T[d][i]
    f32x4 acc2[2][4];
    #pragma unroll
    for (int i = 0; i < 2; ++i)
        #pragma unroll
        for (int j = 0; j < 4; ++j) acc2[i][j] = (f32x4)0.0f;
    #pragma unroll
    for (int kk = 0; kk < 2; ++kk) {
        bf16x8 aV[2], bP[4];
        #pragma unroll
        for (int md = 0; md < 2; ++md) {
            const int d = md * 16 + li;
            int off = (d << 7) + kk * 64 + g * 16;
            off ^= (d & 7) << 4;
            aV[md] = *(const bf16x8*)(vt + off);
        }
        #pragma unroll
        for (int ni = 0; ni < 4; ++ni) {
            const int i = ni * 16 + li;
            int off = (i << 7) + kk * 64 + g * 16;
            off ^= (i & 7) << 4;
            bP[ni] = *(const bf16x8*)(ps + off);
        }
        #pragma unroll
        for (int md = 0; md < 2; ++md)
            #pragma unroll
            for (int ni = 0; ni < 4; ++ni)
                acc2[md][ni] = __builtin_amdgcn_mfma_f32_16x16x32_bf16(
                    aV[md], bP[ni], acc2[md][ni], 0, 0, 0);
    }

    // store O[i][d]
    const size_t obase = (size_t)w * 49 * 384 + h * 32;
    #pragma unroll
    for (int ni = 0; ni < 4; ++ni) {
        const int i = ni * 16 + li;
        if (i < 49) {
            #pragma unroll
            for (int md = 0; md < 2; ++md) {
                const int d0 = md * 16 + g * 4;
                union { short h4[4]; uint2 u2; } pk;
                #pragma unroll
                for (int r = 0; r < 4; ++r) pk.h4[r] = f2bs(acc2[md][ni][r]);
                *(uint2*)&o[obase + (size_t)i * 384 + d0] = pk.u2;
            }
        }
    }
}

// ---------------------------------------------------------------------------
extern "C" void kernel_launch(void* const* d_in, const int* in_sizes, int n_in,
                              void* d_out, int out_size, void* d_ws, size_t ws_size,
                              hipStream_t stream) {
    const float* x      = (const float*)d_in[0];
    const float* n1w    = (const float*)d_in[1];
    const float* n1b    = (const float*)d_in[2];
    const float* qkv_w  = (const float*)d_in[3];
    const float* qkv_b  = (const float*)d_in[4];
    const float* table  = (const float*)d_in[5];
    const float* proj_w = (const float*)d_in[6];
    const float* proj_b = (const float*)d_in[7];
    const float* n2w    = (const float*)d_in[8];
    const float* n2b    = (const float*)d_in[9];
    const float* fc1_w  = (const float*)d_in[10];
    const float* fc1_b  = (const float*)d_in[11];
    const float* fc2_w  = (const float*)d_in[12];
    const float* fc2_b  = (const float*)d_in[13];
    float* out = (float*)d_out;

    char* ws = (char*)d_ws;
    bf16* buf0 = (bf16*)ws;                              // TOK*384 bf16
    bf16* buf1 = (bf16*)(ws + 77070336);                 // qkv / hid
    bf16* wb   = (bf16*)(ws + 77070336 + 308281344);     // bf16 weights

    convert_w_kernel<<<1728, 256, 0, stream>>>(qkv_w, proj_w, fc1_w, fc2_w, wb);
    // 1) LN1 + roll + window partition -> buf0
    ln_kernel<true><<<TOK / 4, 256, 0, stream>>>(x, n1w, n1b, buf0);
    // 2) QKV GEMM -> buf1 (q|k|v, head-major)
    gemm_bt<0><<<784 * 9, 256, 0, stream>>>(buf0, wb, qkv_b,
                                            buf1, nullptr, nullptr, 384, 9);
    // 3) MFMA windowed attention -> buf0
    attn_mfma<<<2048 * 12 / 4, 256, 0, stream>>>(buf1, buf1 + QKV_SEG,
                                                 buf1 + 2 * QKV_SEG, table, buf0);
    // 4) proj GEMM + reverse/roll + residual -> out
    gemm_bt<1><<<784 * 3, 256, 0, stream>>>(buf0, wb + 442368, proj_b,
                                            nullptr, out, x, 384, 3);
    // 5) LN2(y) -> buf0
    ln_kernel<false><<<TOK / 4, 256, 0, stream>>>(out, n2w, n2b, buf0);
    // 6) fc1 + GELU -> buf1
    gemm_bt<2><<<784 * 12, 256, 0, stream>>>(buf0, wb + 589824, fc1_b,
                                             buf1, nullptr, nullptr, 384, 12);
    // 7) fc2 + residual (in-place on out)
    gemm_bt<3><<<784 * 3, 256, 0, stream>>>(buf1, wb + 1179648, fc2_b,
                                            nullptr, out, out, 1536, 3);
}